// Round 12
// baseline (1004.136 us; speedup 1.0000x reference)
//
#include <hip/hip_runtime.h>

#define N_NODES 20000
#define N_EDGES 640000
#define DIM 128
#define NGRAPH 128
#define NLAYER 5
#define EDIM 7
#define TWO_D 256

typedef __bf16 bf16x8 __attribute__((ext_vector_type(8)));
typedef __bf16 bf16x4 __attribute__((ext_vector_type(4)));
typedef __bf16 bf16x2 __attribute__((ext_vector_type(2)));
typedef float  f32x4  __attribute__((ext_vector_type(4)));

__device__ __forceinline__ f32x4 mfma16(bf16x8 a, bf16x8 b, f32x4 c) {
  return __builtin_amdgcn_mfma_f32_16x16x32_bf16(a, b, c, 0, 0, 0);
}

// ---------------- CSR build ----------------
__global__ void k_hist(const int* __restrict__ dst, int* __restrict__ counts) {
  int e = blockIdx.x * blockDim.x + threadIdx.x;
  if (e < N_EDGES) atomicAdd(&counts[dst[e]], 1);
}

__global__ __launch_bounds__(1024) void k_scanA(const int* __restrict__ counts,
    int* __restrict__ local, int* __restrict__ bsum) {
  __shared__ int sd[1024];
  int b = blockIdx.x, tid = threadIdx.x;
  int i = b * 1024 + tid;
  int v = (i < N_NODES) ? counts[i] : 0;
  sd[tid] = v;
  __syncthreads();
  for (int ofs = 1; ofs < 1024; ofs <<= 1) {
    int t = (tid >= ofs) ? sd[tid - ofs] : 0;
    __syncthreads();
    sd[tid] += t;
    __syncthreads();
  }
  if (i <= N_NODES) local[i] = sd[tid] - v;  // exclusive
  if (tid == 1023) bsum[b] = sd[1023];
}

// carry pass + graph-segment starts
__global__ void k_scanB(int* __restrict__ bsum, int* __restrict__ carry,
                        int* __restrict__ offsets, const int* __restrict__ batch,
                        int* __restrict__ gs) {
  int tid = threadIdx.x;
  if (tid == 0) {
    int run = 0;
    for (int b = 0; b < 20; ++b) { carry[b] = run; run += bsum[b]; }
    offsets[N_NODES] = run;
  }
  if (tid <= NGRAPH) {
    if (tid == NGRAPH) gs[NGRAPH] = N_NODES;
    else {
      int lo = 0, hi = N_NODES;
      while (lo < hi) { int mid = (lo + hi) >> 1; if (batch[mid] < tid) lo = mid + 1; else hi = mid; }
      gs[tid] = lo;
    }
  }
}

__global__ __launch_bounds__(1024) void k_scanC(const int* __restrict__ local,
    const int* __restrict__ carry, int* __restrict__ offsets) {
  int i = blockIdx.x * 1024 + threadIdx.x;
  if (i < N_NODES) offsets[i] = local[i] + carry[i >> 10];
}

// fill pass A: only the unavoidable random write (4B perm scatter)
__global__ void k_fillA(const int* __restrict__ dstArr, const int* __restrict__ offsets,
                        int* __restrict__ cursor, int* __restrict__ perm) {
  int e = blockIdx.x * blockDim.x + threadIdx.x;
  if (e >= N_EDGES) return;
  int d = dstArr[e];
  int p = offsets[d] + atomicAdd(&cursor[d], 1);
  perm[p] = e;
}

// fill pass B: coalesced over CSR slots; random READS, sequential writes
__global__ void k_fillB(const int* __restrict__ perm, const int* __restrict__ srcArr,
                        const float* __restrict__ edge_attr,
                        int* __restrict__ csr_src, __bf16* __restrict__ ea_csr) {
  int i = blockIdx.x * blockDim.x + threadIdx.x;
  if (i >= N_EDGES) return;
  int e = perm[i];
  csr_src[i] = srcArr[e];
  const float* ea = edge_attr + (size_t)e * EDIM;
  bf16x8 v;
#pragma unroll
  for (int k = 0; k < EDIM; ++k) v[k] = (__bf16)ea[k];
  v[7] = (__bf16)0.f;
  *(bf16x8*)(ea_csr + (size_t)i * 8) = v;
}

// ---------------- all weight transposes (hi/lo split) in one launch ----------------
__global__ void k_convAll(const float* __restrict__ encW, const float* __restrict__ W1,
    const float* __restrict__ W2,
    __bf16* __restrict__ encT_hi, __bf16* __restrict__ encT_lo,
    __bf16* __restrict__ W1T_hi, __bf16* __restrict__ W1T_lo,
    __bf16* __restrict__ W2T_hi, __bf16* __restrict__ W2T_lo) {
  const int t1 = DIM * DIM;
  const int t2 = NLAYER * DIM * TWO_D;
  const int total = t1 + t2 + t2;
  for (int i = blockIdx.x * blockDim.x + threadIdx.x; i < total;
       i += gridDim.x * blockDim.x) {
    const float* src; __bf16 *dh, *dl; int K, C, idx;
    if (i < t1)            { src = encW; dh = encT_hi; dl = encT_lo; K = DIM;   C = DIM;   idx = i; }
    else if (i < t1 + t2)  { src = W1;   dh = W1T_hi;  dl = W1T_lo;  K = DIM;   C = TWO_D; idx = i - t1; }
    else                   { src = W2;   dh = W2T_hi;  dl = W2T_lo;  K = TWO_D; C = DIM;   idx = i - t1 - t2; }
    int l = idx / (K * C);
    int rem = idx - l * K * C;
    int k = rem / C;
    int c = rem - k * C;
    float v = src[idx];
    __bf16 hi = (__bf16)v;
    __bf16 lo = (__bf16)(v - (float)hi);
    size_t o = (size_t)l * K * C + (size_t)c * K + k;
    dh[o] = hi;
    dl[o] = lo;
  }
}

// ---------------- encoder GEMM: h = x@encW + enc_b + vn_emb (hi/lo out, + pooled0) ----------------
__global__ __launch_bounds__(128) void k_enc(const float* __restrict__ x,
    const __bf16* __restrict__ encT_hi, const __bf16* __restrict__ encT_lo,
    const float* __restrict__ enc_b, const float* __restrict__ vn_emb,
    const int* __restrict__ batch,
    __bf16* __restrict__ h_hi, __bf16* __restrict__ h_lo,
    float* __restrict__ pooled0) {
  int lane = threadIdx.x & 63, wid = threadIdx.x >> 6;
  int rbase = blockIdx.x * 32 + wid * 16;
  int r = rbase + (lane & 15);
  int ko = (lane >> 4) * 8;
  const float* xr = x + (size_t)r * DIM;
  bf16x8 a_hi[4], a_lo[4];
#pragma unroll
  for (int ks = 0; ks < 4; ++ks) {
    f32x4 v0 = *(const f32x4*)(xr + ks * 32 + ko);
    f32x4 v1 = *(const f32x4*)(xr + ks * 32 + ko + 4);
    bf16x8 th, tl;
#pragma unroll
    for (int j = 0; j < 4; ++j) {
      th[j] = (__bf16)v0[j];     tl[j] = (__bf16)(v0[j] - (float)th[j]);
      th[4+j] = (__bf16)v1[j];   tl[4+j] = (__bf16)(v1[j] - (float)th[4+j]);
    }
    a_hi[ks] = th; a_lo[ks] = tl;
  }
  const f32x4 fz = {0.f, 0.f, 0.f, 0.f};
  f32x4 acc[8];
#pragma unroll
  for (int nf = 0; nf < 8; ++nf) acc[nf] = fz;
#pragma unroll
  for (int nf = 0; nf < 8; ++nf) {
    size_t wrow = (size_t)(nf * 16 + (lane & 15)) * DIM + ko;
    const __bf16* bh = encT_hi + wrow;
    const __bf16* bl = encT_lo + wrow;
#pragma unroll
    for (int ks = 0; ks < 4; ++ks) {
      bf16x8 wh = *(const bf16x8*)(bh + ks * 32);
      bf16x8 wl = *(const bf16x8*)(bl + ks * 32);
      acc[nf] = mfma16(a_hi[ks], wh, acc[nf]);
      acc[nf] = mfma16(a_lo[ks], wh, acc[nf]);
      acc[nf] = mfma16(a_hi[ks], wl, acc[nf]);
    }
  }
  int c0 = lane & 15;
  int rr = rbase + (lane >> 4) * 4;
  int bj[4];
#pragma unroll
  for (int j = 0; j < 4; ++j) bj[j] = batch[rr + j];
  float* prep = pooled0 + (size_t)(blockIdx.x & 7) * NGRAPH * DIM;
#pragma unroll
  for (int nf = 0; nf < 8; ++nf) {
    int c = nf * 16 + c0;
    float bias = enc_b[c] + vn_emb[c];
#pragma unroll
    for (int j = 0; j < 4; ++j) {
      float v = acc[nf][j] + bias;
      __bf16 hi = (__bf16)v;
      h_hi[(size_t)(rr + j) * DIM + c] = hi;
      h_lo[(size_t)(rr + j) * DIM + c] = (__bf16)(v - (float)hi);
      atomicAdd(&prep[bj[j] * DIM + c], v);
    }
  }
}

// ---------------- GIN aggregation -> z (hi/lo split) ----------------
// 2 nodes per wave: 4 waves/block = 8 nodes, grid 2500. Joint loop processes
// 2 edges of each node per trip -> 4 gathers in flight over 2 indep chains.
__global__ __launch_bounds__(256) void k_agg(const __bf16* __restrict__ h_hi,
    const __bf16* __restrict__ h_lo, const int* __restrict__ offsets,
    const int* __restrict__ csr_src, const __bf16* __restrict__ ea_csr,
    const float* __restrict__ eW, const float* __restrict__ eB,
    const float* __restrict__ eps, int l,
    __bf16* __restrict__ z_hi, __bf16* __restrict__ z_lo) {
  int tid = threadIdx.x;
  int lane = tid & 63, w = tid >> 6;
  int l2 = lane * 2;
  int n0 = blockIdx.x * 8 + w * 2;
  int n1 = n0 + 1;
  float w0[EDIM], w1[EDIM];
#pragma unroll
  for (int k = 0; k < EDIM; ++k) {
    float2 wv = *(const float2*)(eW + k * DIM + l2);
    w0[k] = wv.x; w1[k] = wv.y;
  }
  float2 ebv = *(const float2*)(eB + l2);
  int i0 = offsets[n0], e0_ = offsets[n0 + 1];
  int i1 = e0_, e1_ = offsets[n1 + 1];   // CSR contiguous: offsets[n1] == offsets[n0+1]
  float a00 = 0.f, a01 = 0.f, a10 = 0.f, a11 = 0.f;

  auto edge = [&](int iu, float& ax, float& ay) {
    int s = csr_src[iu];
    const unsigned* eu = (const unsigned*)(ea_csr + (size_t)iu * 8);
    unsigned u0 = eu[0], u1 = eu[1], u2 = eu[2], u3 = eu[3];
    unsigned hv = *(const unsigned*)(h_hi + (size_t)s * DIM + l2);
    float e0 = __builtin_bit_cast(float, u0 << 16);
    float e1 = __builtin_bit_cast(float, u0 & 0xffff0000u);
    float e2 = __builtin_bit_cast(float, u1 << 16);
    float e3 = __builtin_bit_cast(float, u1 & 0xffff0000u);
    float e4 = __builtin_bit_cast(float, u2 << 16);
    float e5 = __builtin_bit_cast(float, u2 & 0xffff0000u);
    float e6 = __builtin_bit_cast(float, u3 << 16);
    float m0 = __builtin_bit_cast(float, hv << 16) + ebv.x;
    float m1 = __builtin_bit_cast(float, hv & 0xffff0000u) + ebv.y;
    m0 = fmaf(e0, w0[0], m0); m1 = fmaf(e0, w1[0], m1);
    m0 = fmaf(e1, w0[1], m0); m1 = fmaf(e1, w1[1], m1);
    m0 = fmaf(e2, w0[2], m0); m1 = fmaf(e2, w1[2], m1);
    m0 = fmaf(e3, w0[3], m0); m1 = fmaf(e3, w1[3], m1);
    m0 = fmaf(e4, w0[4], m0); m1 = fmaf(e4, w1[4], m1);
    m0 = fmaf(e5, w0[5], m0); m1 = fmaf(e5, w1[5], m1);
    m0 = fmaf(e6, w0[6], m0); m1 = fmaf(e6, w1[6], m1);
    ax += fmaxf(m0, 0.f);
    ay += fmaxf(m1, 0.f);
  };

  while (i0 + 1 < e0_ && i1 + 1 < e1_) {
    int u0 = __builtin_amdgcn_readfirstlane(i0);
    int u1 = __builtin_amdgcn_readfirstlane(i1);
    edge(u0, a00, a01);
    edge(u1, a10, a11);
    edge(u0 + 1, a00, a01);
    edge(u1 + 1, a10, a11);
    i0 += 2; i1 += 2;
  }
  for (; i0 < e0_; ++i0) edge(__builtin_amdgcn_readfirstlane(i0), a00, a01);
  for (; i1 < e1_; ++i1) edge(__builtin_amdgcn_readfirstlane(i1), a10, a11);

  float epsv = 1.f + eps[l];
#pragma unroll
  for (int t = 0; t < 2; ++t) {
    int n = (t == 0) ? n0 : n1;
    float ax = (t == 0) ? a00 : a10;
    float ay = (t == 0) ? a01 : a11;
    unsigned hvh = *(const unsigned*)(h_hi + (size_t)n * DIM + l2);
    unsigned hvl = *(const unsigned*)(h_lo + (size_t)n * DIM + l2);
    float s0 = __builtin_bit_cast(float, hvh << 16) + __builtin_bit_cast(float, hvl << 16);
    float s1 = __builtin_bit_cast(float, hvh & 0xffff0000u) + __builtin_bit_cast(float, hvl & 0xffff0000u);
    float v0 = epsv * s0 + ax;
    float v1 = epsv * s1 + ay;
    __bf16 hi0 = (__bf16)v0, hi1 = (__bf16)v1;
    bf16x2 zh; zh[0] = hi0; zh[1] = hi1;
    bf16x2 zl; zl[0] = (__bf16)(v0 - (float)hi0); zl[1] = (__bf16)(v1 - (float)hi1);
    *(bf16x2*)(z_hi + (size_t)n * DIM + l2) = zh;
    *(bf16x2*)(z_lo + (size_t)n * DIM + l2) = zl;
  }
}

// ---------------- GEMM1: y1 = z @ W1 + b1 (+ BN1 stats), y1 bf16 hi/lo ----------------
__global__ __launch_bounds__(256) void k_gemm1(const __bf16* __restrict__ z_hi,
    const __bf16* __restrict__ z_lo,
    const __bf16* __restrict__ W1T_hi, const __bf16* __restrict__ W1T_lo,
    const float* __restrict__ b1,
    __bf16* __restrict__ y1h, __bf16* __restrict__ y1l,
    float* __restrict__ s1, float* __restrict__ q1) {
  int tid = threadIdx.x;
  int lane = tid & 63, wid = tid >> 6;
  int rowH = wid >> 1, colH = wid & 1;
  int rbase = blockIdx.x * 32 + rowH * 16;
  int r = rbase + (lane & 15);
  int ko = (lane >> 4) * 8;
  bf16x8 a_hi[4], a_lo[4];
#pragma unroll
  for (int ks = 0; ks < 4; ++ks) {
    a_hi[ks] = *(const bf16x8*)(z_hi + (size_t)r * DIM + ks * 32 + ko);
    a_lo[ks] = *(const bf16x8*)(z_lo + (size_t)r * DIM + ks * 32 + ko);
  }
  const f32x4 fz = {0.f, 0.f, 0.f, 0.f};
  f32x4 acc[8];
#pragma unroll
  for (int nf8 = 0; nf8 < 8; ++nf8) acc[nf8] = fz;
#pragma unroll
  for (int nf8 = 0; nf8 < 8; ++nf8) {
    int nf = colH * 8 + nf8;
    size_t wrow = (size_t)(nf * 16 + (lane & 15)) * DIM + ko;
    const __bf16* bh = W1T_hi + wrow;
    const __bf16* bl = W1T_lo + wrow;
#pragma unroll
    for (int ks = 0; ks < 4; ++ks) {
      bf16x8 wh = *(const bf16x8*)(bh + ks * 32);
      bf16x8 wl = *(const bf16x8*)(bl + ks * 32);
      acc[nf8] = mfma16(a_hi[ks], wh, acc[nf8]);
      acc[nf8] = mfma16(a_lo[ks], wh, acc[nf8]);
      acc[nf8] = mfma16(a_hi[ks], wl, acc[nf8]);
    }
  }
  int c0 = lane & 15;
  int rr = rbase + (lane >> 4) * 4;
  int rep = blockIdx.x & 7;
#pragma unroll
  for (int nf8 = 0; nf8 < 8; ++nf8) {
    int c = (colH * 8 + nf8) * 16 + c0;
    float bias = b1[c];
    float s = 0.f, q = 0.f;
#pragma unroll
    for (int j = 0; j < 4; ++j) {
      float v = acc[nf8][j] + bias;
      __bf16 hi = (__bf16)v;
      y1h[(size_t)(rr + j) * TWO_D + c] = hi;
      y1l[(size_t)(rr + j) * TWO_D + c] = (__bf16)(v - (float)hi);
      s += v; q += v * v;
    }
    s += __shfl_xor(s, 16); s += __shfl_xor(s, 32);
    q += __shfl_xor(q, 16); q += __shfl_xor(q, 32);
    if (lane < 16) {
      atomicAdd(&s1[rep * TWO_D + c], s);
      atomicAdd(&q1[rep * TWO_D + c], q);
    }
  }
}

// ---------------- GEMM2: prologue computes BN1 scale/shift from stats ----------------
__global__ __launch_bounds__(256) void k_gemm2(const __bf16* __restrict__ y1h,
    const __bf16* __restrict__ y1l,
    const __bf16* __restrict__ W2T_hi, const __bf16* __restrict__ W2T_lo,
    const float* __restrict__ b2,
    const float* __restrict__ s1, const float* __restrict__ q1,
    const float* __restrict__ bn1g, const float* __restrict__ bn1b,
    float* __restrict__ y2, float* __restrict__ s2, float* __restrict__ q2) {
  __shared__ float sc1s[TWO_D], sh1s[TWO_D];
  int tid = threadIdx.x;
  {
    int c = tid;
    float s = 0.f, q = 0.f;
#pragma unroll
    for (int rep = 0; rep < 8; ++rep) { s += s1[rep * TWO_D + c]; q += q1[rep * TWO_D + c]; }
    float m = s * (1.f / N_NODES);
    float var = q * (1.f / N_NODES) - m * m;
    float a = bn1g[c] / sqrtf(var + 1e-5f);
    sc1s[c] = a; sh1s[c] = bn1b[c] - m * a;
  }
  __syncthreads();
  int lane = tid & 63, wid = tid >> 6;
  int rowH = wid >> 1, colH = wid & 1;
  int rbase = blockIdx.x * 32 + rowH * 16;
  int r = rbase + (lane & 15);
  int ko = (lane >> 4) * 8;
  bf16x8 a_hi[8], a_lo[8];
#pragma unroll
  for (int ks = 0; ks < 8; ++ks) {
    int kb = ks * 32 + ko;
    bf16x8 rh = *(const bf16x8*)(y1h + (size_t)r * TWO_D + kb);
    bf16x8 rl = *(const bf16x8*)(y1l + (size_t)r * TWO_D + kb);
    f32x4 sc0 = *(const f32x4*)(&sc1s[kb]);
    f32x4 sc1 = *(const f32x4*)(&sc1s[kb + 4]);
    f32x4 sh0 = *(const f32x4*)(&sh1s[kb]);
    f32x4 sh1 = *(const f32x4*)(&sh1s[kb + 4]);
    bf16x8 th, tl;
#pragma unroll
    for (int j = 0; j < 4; ++j) {
      float r0 = (float)rh[j] + (float)rl[j];
      float r1 = (float)rh[4 + j] + (float)rl[4 + j];
      float v0 = fmaxf(r0 * sc0[j] + sh0[j], 0.f);
      float v1 = fmaxf(r1 * sc1[j] + sh1[j], 0.f);
      th[j] = (__bf16)v0;     tl[j] = (__bf16)(v0 - (float)th[j]);
      th[4+j] = (__bf16)v1;   tl[4+j] = (__bf16)(v1 - (float)th[4+j]);
    }
    a_hi[ks] = th; a_lo[ks] = tl;
  }
  const f32x4 fz = {0.f, 0.f, 0.f, 0.f};
  f32x4 acc[4];
#pragma unroll
  for (int nf4 = 0; nf4 < 4; ++nf4) acc[nf4] = fz;
#pragma unroll
  for (int nf4 = 0; nf4 < 4; ++nf4) {
    int nf = colH * 4 + nf4;
    size_t wrow = (size_t)(nf * 16 + (lane & 15)) * TWO_D + ko;
    const __bf16* bh = W2T_hi + wrow;
    const __bf16* bl = W2T_lo + wrow;
#pragma unroll
    for (int ks = 0; ks < 8; ++ks) {
      bf16x8 wh = *(const bf16x8*)(bh + ks * 32);
      bf16x8 wl = *(const bf16x8*)(bl + ks * 32);
      acc[nf4] = mfma16(a_hi[ks], wh, acc[nf4]);
      acc[nf4] = mfma16(a_lo[ks], wh, acc[nf4]);
      acc[nf4] = mfma16(a_hi[ks], wl, acc[nf4]);
    }
  }
  int c0 = lane & 15;
  int rr = rbase + (lane >> 4) * 4;
  int rep = blockIdx.x & 7;
#pragma unroll
  for (int nf4 = 0; nf4 < 4; ++nf4) {
    int c = (colH * 4 + nf4) * 16 + c0;
    float bias = b2[c];
    float s = 0.f, q = 0.f;
#pragma unroll
    for (int j = 0; j < 4; ++j) {
      float v = acc[nf4][j] + bias;
      y2[(size_t)(rr + j) * DIM + c] = v;
      s += v; q += v * v;
    }
    s += __shfl_xor(s, 16); s += __shfl_xor(s, 32);
    q += __shfl_xor(q, 16); q += __shfl_xor(q, 32);
    if (lane < 16) {
      atomicAdd(&s2[rep * DIM + c], s);
      atomicAdd(&q2[rep * DIM + c], q);
    }
  }
}

// ---------------- vnode GEMM1: prologue folds pooled reps + vn term ----------------
__global__ __launch_bounds__(256) void k_vgemm1(const float* __restrict__ pooled,
    const float* __restrict__ vn_emb, const float* __restrict__ vnr,
    const float* __restrict__ sv2p, const float* __restrict__ qv2p,
    const float* __restrict__ vbn2g, const float* __restrict__ vbn2b, int use_stats,
    const float* __restrict__ W1, const float* __restrict__ b1,
    float* __restrict__ tv, float* __restrict__ sv1, float* __restrict__ qv1) {
  __shared__ float row[DIM];
  int g = blockIdx.x, tid = threadIdx.x;
  if (tid < DIM) {
    float vnterm;
    if (use_stats) {
      float s = 0.f, q = 0.f;
#pragma unroll
      for (int rep = 0; rep < 8; ++rep) { s += sv2p[rep * DIM + tid]; q += qv2p[rep * DIM + tid]; }
      float m = s * (1.f / NGRAPH);
      float var = q * (1.f / NGRAPH) - m * m;
      float a = vbn2g[tid] / sqrtf(var + 1e-5f);
      vnterm = fmaxf(vnr[g * DIM + tid] * a + (vbn2b[tid] - m * a), 0.f);
    } else {
      vnterm = vn_emb[tid];
    }
    float ps = 0.f;
#pragma unroll
    for (int rep = 0; rep < 8; ++rep) ps += pooled[(size_t)rep * NGRAPH * DIM + g * DIM + tid];
    row[tid] = ps + vnterm;
  }
  __syncthreads();
  int c = tid;
  float acc = b1[c];
  for (int k = 0; k < DIM; ++k) acc = fmaf(row[k], W1[k * TWO_D + c], acc);
  tv[g * TWO_D + c] = acc;
  int rep = g & 7;
  atomicAdd(&sv1[rep * TWO_D + c], acc);
  atomicAdd(&qv1[rep * TWO_D + c], acc * acc);
}

// ---------------- vnode BN1+relu+GEMM2 (+ col stats) ----------------
__global__ __launch_bounds__(256) void k_vgemm2(const float* __restrict__ tv,
    const float* __restrict__ sv1, const float* __restrict__ qv1,
    const float* __restrict__ bn1g, const float* __restrict__ bn1b,
    const float* __restrict__ W2, const float* __restrict__ b2,
    float* __restrict__ vnr, float* __restrict__ sv2, float* __restrict__ qv2) {
  __shared__ float trow[TWO_D];
  int g = blockIdx.x, tid = threadIdx.x;
  {
    float s = 0.f, q = 0.f;
#pragma unroll
    for (int rep = 0; rep < 8; ++rep) { s += sv1[rep * TWO_D + tid]; q += qv1[rep * TWO_D + tid]; }
    float m = s * (1.f / NGRAPH);
    float var = q * (1.f / NGRAPH) - m * m;
    float a = bn1g[tid] / sqrtf(var + 1e-5f);
    trow[tid] = fmaxf(tv[g * TWO_D + tid] * a + (bn1b[tid] - m * a), 0.f);
  }
  __syncthreads();
  if (tid < DIM) {
    float acc = b2[tid];
    for (int k = 0; k < TWO_D; ++k) acc = fmaf(trow[k], W2[k * DIM + tid], acc);
    vnr[g * DIM + tid] = acc;
    int rep = g & 7;
    atomicAdd(&sv2[rep * DIM + tid], acc);
    atomicAdd(&qv2[rep * DIM + tid], acc * acc);
  }
}

// ---------------- BN2 finalize + relu + vn gather -> h_hi/h_lo (+ pooledNext) ----------------
__global__ __launch_bounds__(256) void k_bn2hin(const float* __restrict__ y2,
    const float* __restrict__ s2, const float* __restrict__ q2,
    const float* __restrict__ bng, const float* __restrict__ bnb,
    const float* __restrict__ vnr, const float* __restrict__ sv2,
    const float* __restrict__ qv2, const float* __restrict__ vbn2g,
    const float* __restrict__ vbn2b, const int* __restrict__ batch,
    __bf16* __restrict__ h_hi, __bf16* __restrict__ h_lo,
    float* __restrict__ pooledNext) {
  __shared__ float sc2s[DIM], sh2s[DIM], scvn[DIM], shvn[DIM];
  int tid = threadIdx.x;
  if (tid < DIM) {
    float s = 0.f, q = 0.f;
#pragma unroll
    for (int rep = 0; rep < 8; ++rep) { s += s2[rep * DIM + tid]; q += q2[rep * DIM + tid]; }
    float m = s * (1.f / N_NODES);
    float var = q * (1.f / N_NODES) - m * m;
    float a = bng[tid] / sqrtf(var + 1e-5f);
    sc2s[tid] = a; sh2s[tid] = bnb[tid] - m * a;
    float sv = 0.f, qv = 0.f;
#pragma unroll
    for (int rep = 0; rep < 8; ++rep) { sv += sv2[rep * DIM + tid]; qv += qv2[rep * DIM + tid]; }
    float mv = sv * (1.f / NGRAPH);
    float varv = qv * (1.f / NGRAPH) - mv * mv;
    float av = vbn2g[tid] / sqrtf(varv + 1e-5f);
    scvn[tid] = av; shvn[tid] = vbn2b[tid] - mv * av;
  }
  __syncthreads();
  int idx = blockIdx.x * 256 + tid;
  if (idx >= N_NODES * (DIM / 4)) return;
  int c4 = idx & 31;
  int row = idx >> 5;
  f32x4 y = ((const f32x4*)y2)[idx];
  f32x4 scv = ((const f32x4*)sc2s)[c4];
  f32x4 shv = ((const f32x4*)sh2s)[c4];
  f32x4 vsc = ((const f32x4*)scvn)[c4];
  f32x4 vsh = ((const f32x4*)shvn)[c4];
  int b = batch[row];
  f32x4 vr = ((const f32x4*)vnr)[b * 32 + c4];
  float* prep = pooledNext + (size_t)(blockIdx.x & 7) * NGRAPH * DIM + (size_t)b * DIM + c4 * 4;
  bf16x4 oh, ol;
#pragma unroll
  for (int j = 0; j < 4; ++j) {
    float vnv = fmaxf(vr[j] * vsc[j] + vsh[j], 0.f);
    float o = fmaxf(y[j] * scv[j] + shv[j], 0.f) + vnv;
    __bf16 hi = (__bf16)o;
    oh[j] = hi;
    ol[j] = (__bf16)(o - (float)hi);
    atomicAdd(&prep[j], o);
  }
  ((bf16x4*)h_hi)[idx] = oh;
  ((bf16x4*)h_lo)[idx] = ol;
}

__global__ __launch_bounds__(256) void k_out(const float* __restrict__ y2,
    const float* __restrict__ s2, const float* __restrict__ q2,
    const float* __restrict__ bng, const float* __restrict__ bnb,
    float* __restrict__ out) {
  __shared__ float sc2s[DIM], sh2s[DIM];
  int tid = threadIdx.x;
  if (tid < DIM) {
    float s = 0.f, q = 0.f;
#pragma unroll
    for (int rep = 0; rep < 8; ++rep) { s += s2[rep * DIM + tid]; q += q2[rep * DIM + tid]; }
    float m = s * (1.f / N_NODES);
    float var = q * (1.f / N_NODES) - m * m;
    float a = bng[tid] / sqrtf(var + 1e-5f);
    sc2s[tid] = a; sh2s[tid] = bnb[tid] - m * a;
  }
  __syncthreads();
  int idx = blockIdx.x * 256 + tid;
  if (idx >= N_NODES * (DIM / 4)) return;
  int c4 = idx & 31;
  f32x4 y = ((const f32x4*)y2)[idx];
  f32x4 scv = ((const f32x4*)sc2s)[c4];
  f32x4 shv = ((const f32x4*)sh2s)[c4];
  f32x4 o;
#pragma unroll
  for (int j = 0; j < 4; ++j) o[j] = y[j] * scv[j] + shv[j];
  ((f32x4*)out)[idx] = o;
}

// ---------------- host ----------------
extern "C" void kernel_launch(void* const* d_in, const int* in_sizes, int n_in,
                              void* d_out, int out_size, void* d_ws, size_t ws_size,
                              hipStream_t stream) {
  const float* x         = (const float*)d_in[0];
  const float* edge_attr = (const float*)d_in[1];
  const int*   edge_index= (const int*)d_in[2];
  const int*   batch     = (const int*)d_in[3];
  const float* enc_W     = (const float*)d_in[4];
  const float* enc_b     = (const float*)d_in[5];
  const float* vn_emb    = (const float*)d_in[6];
  const float* eps       = (const float*)d_in[7];
  const float* edge_W    = (const float*)d_in[8];
  const float* edge_b    = (const float*)d_in[9];
  const float* mlp_W1    = (const float*)d_in[10];
  const float* mlp_b1    = (const float*)d_in[11];
  const float* mlp_bn1_g = (const float*)d_in[12];
  const float* mlp_bn1_b = (const float*)d_in[13];
  const float* mlp_W2    = (const float*)d_in[14];
  const float* mlp_b2    = (const float*)d_in[15];
  const float* bn_g      = (const float*)d_in[16];
  const float* bn_b      = (const float*)d_in[17];
  const float* vn_W1     = (const float*)d_in[18];
  const float* vn_b1     = (const float*)d_in[19];
  const float* vn_bn1_g  = (const float*)d_in[20];
  const float* vn_bn1_b  = (const float*)d_in[21];
  const float* vn_W2     = (const float*)d_in[22];
  const float* vn_b2     = (const float*)d_in[23];
  const float* vn_bn2_g  = (const float*)d_in[24];
  const float* vn_bn2_b  = (const float*)d_in[25];

  char* wsb = (char*)d_ws;
  size_t off = 0;
  auto take = [&](size_t bytes) -> void* {
    void* p = wsb + off;
    off += (bytes + 255) & ~(size_t)255;
    return p;
  };
  // memset region: counts+cursor | stats | pooled[5][8][NGRAPH][DIM]
  const size_t POOLED_LAYER = (size_t)8 * NGRAPH * DIM;   // floats per layer
  int*    counts  = (int*)take((size_t)2 * N_NODES * 4);
  int*    cursor  = counts + N_NODES;
  float*  stats   = (float*)take((size_t)NLAYER * 12288 * 4);
  float*  pooledL = (float*)take((size_t)NLAYER * POOLED_LAYER * 4);
  size_t  memset_bytes = (size_t)2 * N_NODES * 4 + (size_t)NLAYER * 12288 * 4
                       + (size_t)NLAYER * POOLED_LAYER * 4;
  __bf16* h_hi    = (__bf16*)take((size_t)N_NODES * DIM * 2);
  __bf16* h_lo    = (__bf16*)take((size_t)N_NODES * DIM * 2);
  float*  y2      = (float*)take((size_t)N_NODES * DIM * 4);
  __bf16* y1h     = (__bf16*)take((size_t)N_NODES * TWO_D * 2);
  __bf16* y1l     = (__bf16*)take((size_t)N_NODES * TWO_D * 2);
  __bf16* z_hi    = (__bf16*)take((size_t)N_NODES * DIM * 2);
  __bf16* z_lo    = (__bf16*)take((size_t)N_NODES * DIM * 2);
  int*    csr_src = (int*)take((size_t)N_EDGES * 4);
  __bf16* ea_csr  = (__bf16*)take((size_t)N_EDGES * 8 * 2);
  int*    perm    = (int*)take((size_t)N_EDGES * 4);
  int*    offsets = (int*)take((size_t)(N_NODES + 1) * 4);
  int*    slocal  = (int*)take((size_t)(N_NODES + 1024) * 4);
  int*    sbsum   = (int*)take(64 * 4);
  int*    scarry  = sbsum + 32;
  int*    gs      = (int*)take((size_t)(NGRAPH + 1) * 4);
  float*  tv      = (float*)take((size_t)NGRAPH * TWO_D * 4);
  float*  vnr     = (float*)take((size_t)NGRAPH * DIM * 4);
  __bf16* encT_hi = (__bf16*)take((size_t)DIM * DIM * 2);
  __bf16* encT_lo = (__bf16*)take((size_t)DIM * DIM * 2);
  __bf16* W1T_hi  = (__bf16*)take((size_t)NLAYER * DIM * TWO_D * 2);
  __bf16* W1T_lo  = (__bf16*)take((size_t)NLAYER * DIM * TWO_D * 2);
  __bf16* W2T_hi  = (__bf16*)take((size_t)NLAYER * TWO_D * DIM * 2);
  __bf16* W2T_lo  = (__bf16*)take((size_t)NLAYER * TWO_D * DIM * 2);
  if (off > ws_size) return;

  const int* srcArr = edge_index;
  const int* dstArr = edge_index + N_EDGES;

  hipMemsetAsync(counts, 0, memset_bytes, stream);

  k_hist<<<N_EDGES / 256, 256, 0, stream>>>(dstArr, counts);
  k_scanA<<<20, 1024, 0, stream>>>(counts, slocal, sbsum);
  k_scanB<<<1, 256, 0, stream>>>(sbsum, scarry, offsets, batch, gs);
  k_scanC<<<20, 1024, 0, stream>>>(slocal, scarry, offsets);
  k_fillA<<<N_EDGES / 256, 256, 0, stream>>>(dstArr, offsets, cursor, perm);
  k_fillB<<<N_EDGES / 256, 256, 0, stream>>>(perm, srcArr, edge_attr, csr_src, ea_csr);
  k_convAll<<<336, 1024, 0, stream>>>(enc_W, mlp_W1, mlp_W2,
      encT_hi, encT_lo, W1T_hi, W1T_lo, W2T_hi, W2T_lo);
  k_enc<<<N_NODES / 32, 128, 0, stream>>>(x, encT_hi, encT_lo, enc_b, vn_emb,
      batch, h_hi, h_lo, pooledL);

  for (int l = 0; l < NLAYER; ++l) {
    float* s1  = stats + (size_t)l * 12288;
    float* q1  = s1 + 2048;
    float* s2  = s1 + 4096;
    float* q2  = s1 + 5120;
    float* sv1 = s1 + 6144;
    float* qv1 = s1 + 8192;
    float* sv2 = s1 + 10240;
    float* qv2 = s1 + 11264;
    k_agg<<<N_NODES / 8, 256, 0, stream>>>(h_hi, h_lo, offsets, csr_src, ea_csr,
        edge_W + (size_t)l * EDIM * DIM, edge_b + (size_t)l * DIM, eps, l, z_hi, z_lo);
    k_gemm1<<<N_NODES / 32, 256, 0, stream>>>(z_hi, z_lo,
        W1T_hi + (size_t)l * DIM * TWO_D, W1T_lo + (size_t)l * DIM * TWO_D,
        mlp_b1 + (size_t)l * TWO_D, y1h, y1l, s1, q1);
    k_gemm2<<<N_NODES / 32, 256, 0, stream>>>(y1h, y1l,
        W2T_hi + (size_t)l * TWO_D * DIM, W2T_lo + (size_t)l * TWO_D * DIM,
        mlp_b2 + (size_t)l * DIM, s1, q1,
        mlp_bn1_g + (size_t)l * TWO_D, mlp_bn1_b + (size_t)l * TWO_D,
        y2, s2, q2);
    if (l < NLAYER - 1) {
      const float* psv2 = (l == 0) ? nullptr : stats + (size_t)(l - 1) * 12288 + 10240;
      const float* pqv2 = (l == 0) ? nullptr : stats + (size_t)(l - 1) * 12288 + 11264;
      k_vgemm1<<<NGRAPH, 256, 0, stream>>>(pooledL + (size_t)l * POOLED_LAYER,
          vn_emb, vnr, psv2, pqv2,
          (l == 0) ? nullptr : vn_bn2_g + (size_t)(l - 1) * DIM,
          (l == 0) ? nullptr : vn_bn2_b + (size_t)(l - 1) * DIM,
          (l == 0) ? 0 : 1,
          vn_W1 + (size_t)l * DIM * TWO_D, vn_b1 + (size_t)l * TWO_D,
          tv, sv1, qv1);
      k_vgemm2<<<NGRAPH, 256, 0, stream>>>(tv, sv1, qv1,
          vn_bn1_g + (size_t)l * TWO_D, vn_bn1_b + (size_t)l * TWO_D,
          vn_W2 + (size_t)l * TWO_D * DIM, vn_b2 + (size_t)l * DIM,
          vnr, sv2, qv2);
      k_bn2hin<<<(N_NODES * 32) / 256, 256, 0, stream>>>(y2, s2, q2,
          bn_g + (size_t)l * DIM, bn_b + (size_t)l * DIM,
          vnr, sv2, qv2, vn_bn2_g + (size_t)l * DIM, vn_bn2_b + (size_t)l * DIM,
          batch, h_hi, h_lo, pooledL + (size_t)(l + 1) * POOLED_LAYER);
    } else {
      k_out<<<(N_NODES * 32) / 256, 256, 0, stream>>>(y2, s2, q2,
          bn_g + (size_t)l * DIM, bn_b + (size_t)l * DIM, (float*)d_out);
    }
  }
}

// Round 13
// 785.644 us; speedup vs baseline: 1.2781x; 1.2781x over previous
//
#include <hip/hip_runtime.h>

#define N_NODES 20000
#define N_EDGES 640000
#define DIM 128
#define NGRAPH 128
#define NLAYER 5
#define EDIM 7
#define TWO_D 256

typedef __bf16 bf16x8 __attribute__((ext_vector_type(8)));
typedef __bf16 bf16x4 __attribute__((ext_vector_type(4)));
typedef __bf16 bf16x2 __attribute__((ext_vector_type(2)));
typedef float  f32x4  __attribute__((ext_vector_type(4)));

__device__ __forceinline__ f32x4 mfma16(bf16x8 a, bf16x8 b, f32x4 c) {
  return __builtin_amdgcn_mfma_f32_16x16x32_bf16(a, b, c, 0, 0, 0);
}

// ---------------- CSR build ----------------
__global__ void k_hist(const int* __restrict__ dst, int* __restrict__ counts) {
  int e = blockIdx.x * blockDim.x + threadIdx.x;
  if (e < N_EDGES) atomicAdd(&counts[dst[e]], 1);
}

__global__ __launch_bounds__(1024) void k_scanA(const int* __restrict__ counts,
    int* __restrict__ local, int* __restrict__ bsum) {
  __shared__ int sd[1024];
  int b = blockIdx.x, tid = threadIdx.x;
  int i = b * 1024 + tid;
  int v = (i < N_NODES) ? counts[i] : 0;
  sd[tid] = v;
  __syncthreads();
  for (int ofs = 1; ofs < 1024; ofs <<= 1) {
    int t = (tid >= ofs) ? sd[tid - ofs] : 0;
    __syncthreads();
    sd[tid] += t;
    __syncthreads();
  }
  if (i <= N_NODES) local[i] = sd[tid] - v;  // exclusive
  if (tid == 1023) bsum[b] = sd[1023];
}

// carry pass + graph-segment starts
__global__ void k_scanB(int* __restrict__ bsum, int* __restrict__ carry,
                        int* __restrict__ offsets, const int* __restrict__ batch,
                        int* __restrict__ gs) {
  int tid = threadIdx.x;
  if (tid == 0) {
    int run = 0;
    for (int b = 0; b < 20; ++b) { carry[b] = run; run += bsum[b]; }
    offsets[N_NODES] = run;
  }
  if (tid <= NGRAPH) {
    if (tid == NGRAPH) gs[NGRAPH] = N_NODES;
    else {
      int lo = 0, hi = N_NODES;
      while (lo < hi) { int mid = (lo + hi) >> 1; if (batch[mid] < tid) lo = mid + 1; else hi = mid; }
      gs[tid] = lo;
    }
  }
}

__global__ __launch_bounds__(1024) void k_scanC(const int* __restrict__ local,
    const int* __restrict__ carry, int* __restrict__ offsets) {
  int i = blockIdx.x * 1024 + threadIdx.x;
  if (i < N_NODES) offsets[i] = local[i] + carry[i >> 10];
}

// fill pass A: only the unavoidable random write (4B perm scatter)
__global__ void k_fillA(const int* __restrict__ dstArr, const int* __restrict__ offsets,
                        int* __restrict__ cursor, int* __restrict__ perm) {
  int e = blockIdx.x * blockDim.x + threadIdx.x;
  if (e >= N_EDGES) return;
  int d = dstArr[e];
  int p = offsets[d] + atomicAdd(&cursor[d], 1);
  perm[p] = e;
}

// fill pass B: coalesced over CSR slots; random READS, sequential writes
__global__ void k_fillB(const int* __restrict__ perm, const int* __restrict__ srcArr,
                        const float* __restrict__ edge_attr,
                        int* __restrict__ csr_src, __bf16* __restrict__ ea_csr) {
  int i = blockIdx.x * blockDim.x + threadIdx.x;
  if (i >= N_EDGES) return;
  int e = perm[i];
  csr_src[i] = srcArr[e];
  const float* ea = edge_attr + (size_t)e * EDIM;
  bf16x8 v;
#pragma unroll
  for (int k = 0; k < EDIM; ++k) v[k] = (__bf16)ea[k];
  v[7] = (__bf16)0.f;
  *(bf16x8*)(ea_csr + (size_t)i * 8) = v;
}

// ---------------- all weight transposes (hi/lo split) in one launch ----------------
__global__ void k_convAll(const float* __restrict__ encW, const float* __restrict__ W1,
    const float* __restrict__ W2,
    __bf16* __restrict__ encT_hi, __bf16* __restrict__ encT_lo,
    __bf16* __restrict__ W1T_hi, __bf16* __restrict__ W1T_lo,
    __bf16* __restrict__ W2T_hi, __bf16* __restrict__ W2T_lo) {
  const int t1 = DIM * DIM;
  const int t2 = NLAYER * DIM * TWO_D;
  const int total = t1 + t2 + t2;
  for (int i = blockIdx.x * blockDim.x + threadIdx.x; i < total;
       i += gridDim.x * blockDim.x) {
    const float* src; __bf16 *dh, *dl; int K, C, idx;
    if (i < t1)            { src = encW; dh = encT_hi; dl = encT_lo; K = DIM;   C = DIM;   idx = i; }
    else if (i < t1 + t2)  { src = W1;   dh = W1T_hi;  dl = W1T_lo;  K = DIM;   C = TWO_D; idx = i - t1; }
    else                   { src = W2;   dh = W2T_hi;  dl = W2T_lo;  K = TWO_D; C = DIM;   idx = i - t1 - t2; }
    int l = idx / (K * C);
    int rem = idx - l * K * C;
    int k = rem / C;
    int c = rem - k * C;
    float v = src[idx];
    __bf16 hi = (__bf16)v;
    __bf16 lo = (__bf16)(v - (float)hi);
    size_t o = (size_t)l * K * C + (size_t)c * K + k;
    dh[o] = hi;
    dl[o] = lo;
  }
}

__global__ void k_vninit(const float* __restrict__ vn_emb, float* __restrict__ vn) {
  int i = blockIdx.x * blockDim.x + threadIdx.x;
  if (i < NGRAPH * DIM) vn[i] = vn_emb[i & (DIM - 1)];
}

// ---------------- encoder GEMM: h = x @ encW + enc_b + vn_emb (hi/lo out) ----------------
__global__ __launch_bounds__(128) void k_enc(const float* __restrict__ x,
    const __bf16* __restrict__ encT_hi, const __bf16* __restrict__ encT_lo,
    const float* __restrict__ enc_b, const float* __restrict__ vn_emb,
    __bf16* __restrict__ h_hi, __bf16* __restrict__ h_lo) {
  int lane = threadIdx.x & 63, wid = threadIdx.x >> 6;
  int rbase = blockIdx.x * 32 + wid * 16;
  int r = rbase + (lane & 15);
  int ko = (lane >> 4) * 8;
  const float* xr = x + (size_t)r * DIM;
  bf16x8 a_hi[4], a_lo[4];
#pragma unroll
  for (int ks = 0; ks < 4; ++ks) {
    f32x4 v0 = *(const f32x4*)(xr + ks * 32 + ko);
    f32x4 v1 = *(const f32x4*)(xr + ks * 32 + ko + 4);
    bf16x8 th, tl;
#pragma unroll
    for (int j = 0; j < 4; ++j) {
      th[j] = (__bf16)v0[j];     tl[j] = (__bf16)(v0[j] - (float)th[j]);
      th[4+j] = (__bf16)v1[j];   tl[4+j] = (__bf16)(v1[j] - (float)th[4+j]);
    }
    a_hi[ks] = th; a_lo[ks] = tl;
  }
  const f32x4 fz = {0.f, 0.f, 0.f, 0.f};
  f32x4 acc[8];
#pragma unroll
  for (int nf = 0; nf < 8; ++nf) acc[nf] = fz;
#pragma unroll
  for (int nf = 0; nf < 8; ++nf) {
    size_t wrow = (size_t)(nf * 16 + (lane & 15)) * DIM + ko;
    const __bf16* bh = encT_hi + wrow;
    const __bf16* bl = encT_lo + wrow;
#pragma unroll
    for (int ks = 0; ks < 4; ++ks) {
      bf16x8 wh = *(const bf16x8*)(bh + ks * 32);
      bf16x8 wl = *(const bf16x8*)(bl + ks * 32);
      acc[nf] = mfma16(a_hi[ks], wh, acc[nf]);
      acc[nf] = mfma16(a_lo[ks], wh, acc[nf]);
      acc[nf] = mfma16(a_hi[ks], wl, acc[nf]);
    }
  }
  int c0 = lane & 15;
  int rr = rbase + (lane >> 4) * 4;
#pragma unroll
  for (int nf = 0; nf < 8; ++nf) {
    int c = nf * 16 + c0;
    float bias = enc_b[c] + vn_emb[c];
#pragma unroll
    for (int j = 0; j < 4; ++j) {
      float v = acc[nf][j] + bias;
      __bf16 hi = (__bf16)v;
      h_hi[(size_t)(rr + j) * DIM + c] = hi;
      h_lo[(size_t)(rr + j) * DIM + c] = (__bf16)(v - (float)hi);
    }
  }
}

// ---------------- per-graph pool: pooled = segsum(h_hi) + vn ----------------
__global__ __launch_bounds__(1024) void k_pool(const __bf16* __restrict__ h_hi,
    const int* __restrict__ gs, const float* __restrict__ vnbuf,
    const float* __restrict__ vnr, const float* __restrict__ sv2,
    const float* __restrict__ qv2, const float* __restrict__ bn2g,
    const float* __restrict__ bn2b, int use_stats,
    float* __restrict__ pooled) {
  __shared__ float red[8][DIM];
  __shared__ float vns[DIM];
  int tid = threadIdx.x;
  int g = blockIdx.x;
  if (tid < DIM) {
    if (use_stats) {
      float s = 0.f, q = 0.f;
#pragma unroll
      for (int rep = 0; rep < 8; ++rep) { s += sv2[rep * DIM + tid]; q += qv2[rep * DIM + tid]; }
      float m = s * (1.f / NGRAPH);
      float var = q * (1.f / NGRAPH) - m * m;
      float a = bn2g[tid] / sqrtf(var + 1e-5f);
      vns[tid] = fmaxf(vnr[g * DIM + tid] * a + (bn2b[tid] - m * a), 0.f);
    } else {
      vns[tid] = vnbuf[g * DIM + tid];
    }
  }
  __syncthreads();
  int d = tid & 127, slot = tid >> 7;
  int lo = gs[g], hi = gs[g + 1];
  float acc = 0.f;
  for (int n = lo + slot; n < hi; n += 8)
    acc += (float)h_hi[(size_t)n * DIM + d];
  red[slot][d] = acc;
  __syncthreads();
  if (slot == 0) {
    float t = vns[d];
#pragma unroll
    for (int s2 = 0; s2 < 8; ++s2) t += red[s2][d];
    pooled[g * DIM + d] = t;
  }
}

// ---------------- GIN aggregation -> z (hi/lo split) ----------------
// 2 nodes per wave: 4 waves/block = 8 nodes, grid 2500. Joint loop processes
// 2 edges of each node per trip -> 4 gathers in flight over 2 indep chains.
__global__ __launch_bounds__(256) void k_agg(const __bf16* __restrict__ h_hi,
    const __bf16* __restrict__ h_lo, const int* __restrict__ offsets,
    const int* __restrict__ csr_src, const __bf16* __restrict__ ea_csr,
    const float* __restrict__ eW, const float* __restrict__ eB,
    const float* __restrict__ eps, int l,
    __bf16* __restrict__ z_hi, __bf16* __restrict__ z_lo) {
  int tid = threadIdx.x;
  int lane = tid & 63, w = tid >> 6;
  int l2 = lane * 2;
  int n0 = blockIdx.x * 8 + w * 2;
  int n1 = n0 + 1;
  float w0[EDIM], w1[EDIM];
#pragma unroll
  for (int k = 0; k < EDIM; ++k) {
    float2 wv = *(const float2*)(eW + k * DIM + l2);
    w0[k] = wv.x; w1[k] = wv.y;
  }
  float2 ebv = *(const float2*)(eB + l2);
  int i0 = offsets[n0], e0_ = offsets[n0 + 1];
  int i1 = e0_, e1_ = offsets[n1 + 1];
  float a00 = 0.f, a01 = 0.f, a10 = 0.f, a11 = 0.f;

  auto edge = [&](int iu, float& ax, float& ay) {
    int s = csr_src[iu];
    const unsigned* eu = (const unsigned*)(ea_csr + (size_t)iu * 8);
    unsigned u0 = eu[0], u1 = eu[1], u2 = eu[2], u3 = eu[3];
    unsigned hv = *(const unsigned*)(h_hi + (size_t)s * DIM + l2);
    float e0 = __builtin_bit_cast(float, u0 << 16);
    float e1 = __builtin_bit_cast(float, u0 & 0xffff0000u);
    float e2 = __builtin_bit_cast(float, u1 << 16);
    float e3 = __builtin_bit_cast(float, u1 & 0xffff0000u);
    float e4 = __builtin_bit_cast(float, u2 << 16);
    float e5 = __builtin_bit_cast(float, u2 & 0xffff0000u);
    float e6 = __builtin_bit_cast(float, u3 << 16);
    float m0 = __builtin_bit_cast(float, hv << 16) + ebv.x;
    float m1 = __builtin_bit_cast(float, hv & 0xffff0000u) + ebv.y;
    m0 = fmaf(e0, w0[0], m0); m1 = fmaf(e0, w1[0], m1);
    m0 = fmaf(e1, w0[1], m0); m1 = fmaf(e1, w1[1], m1);
    m0 = fmaf(e2, w0[2], m0); m1 = fmaf(e2, w1[2], m1);
    m0 = fmaf(e3, w0[3], m0); m1 = fmaf(e3, w1[3], m1);
    m0 = fmaf(e4, w0[4], m0); m1 = fmaf(e4, w1[4], m1);
    m0 = fmaf(e5, w0[5], m0); m1 = fmaf(e5, w1[5], m1);
    m0 = fmaf(e6, w0[6], m0); m1 = fmaf(e6, w1[6], m1);
    ax += fmaxf(m0, 0.f);
    ay += fmaxf(m1, 0.f);
  };

  while (i0 + 1 < e0_ && i1 + 1 < e1_) {
    int u0 = __builtin_amdgcn_readfirstlane(i0);
    int u1 = __builtin_amdgcn_readfirstlane(i1);
    edge(u0, a00, a01);
    edge(u1, a10, a11);
    edge(u0 + 1, a00, a01);
    edge(u1 + 1, a10, a11);
    i0 += 2; i1 += 2;
  }
  for (; i0 < e0_; ++i0) edge(__builtin_amdgcn_readfirstlane(i0), a00, a01);
  for (; i1 < e1_; ++i1) edge(__builtin_amdgcn_readfirstlane(i1), a10, a11);

  float epsv = 1.f + eps[l];
#pragma unroll
  for (int t = 0; t < 2; ++t) {
    int n = (t == 0) ? n0 : n1;
    float ax = (t == 0) ? a00 : a10;
    float ay = (t == 0) ? a01 : a11;
    unsigned hvh = *(const unsigned*)(h_hi + (size_t)n * DIM + l2);
    unsigned hvl = *(const unsigned*)(h_lo + (size_t)n * DIM + l2);
    float s0 = __builtin_bit_cast(float, hvh << 16) + __builtin_bit_cast(float, hvl << 16);
    float s1 = __builtin_bit_cast(float, hvh & 0xffff0000u) + __builtin_bit_cast(float, hvl & 0xffff0000u);
    float v0 = epsv * s0 + ax;
    float v1 = epsv * s1 + ay;
    __bf16 hi0 = (__bf16)v0, hi1 = (__bf16)v1;
    bf16x2 zh; zh[0] = hi0; zh[1] = hi1;
    bf16x2 zl; zl[0] = (__bf16)(v0 - (float)hi0); zl[1] = (__bf16)(v1 - (float)hi1);
    *(bf16x2*)(z_hi + (size_t)n * DIM + l2) = zh;
    *(bf16x2*)(z_lo + (size_t)n * DIM + l2) = zl;
  }
}

// ---------------- GEMM1: y1 = z @ W1 + b1 (+ BN1 stats), y1 bf16 hi/lo ----------------
__global__ __launch_bounds__(256) void k_gemm1(const __bf16* __restrict__ z_hi,
    const __bf16* __restrict__ z_lo,
    const __bf16* __restrict__ W1T_hi, const __bf16* __restrict__ W1T_lo,
    const float* __restrict__ b1,
    __bf16* __restrict__ y1h, __bf16* __restrict__ y1l,
    float* __restrict__ s1, float* __restrict__ q1) {
  int tid = threadIdx.x;
  int lane = tid & 63, wid = tid >> 6;
  int rowH = wid >> 1, colH = wid & 1;
  int rbase = blockIdx.x * 32 + rowH * 16;
  int r = rbase + (lane & 15);
  int ko = (lane >> 4) * 8;
  bf16x8 a_hi[4], a_lo[4];
#pragma unroll
  for (int ks = 0; ks < 4; ++ks) {
    a_hi[ks] = *(const bf16x8*)(z_hi + (size_t)r * DIM + ks * 32 + ko);
    a_lo[ks] = *(const bf16x8*)(z_lo + (size_t)r * DIM + ks * 32 + ko);
  }
  const f32x4 fz = {0.f, 0.f, 0.f, 0.f};
  f32x4 acc[8];
#pragma unroll
  for (int nf8 = 0; nf8 < 8; ++nf8) acc[nf8] = fz;
#pragma unroll
  for (int nf8 = 0; nf8 < 8; ++nf8) {
    int nf = colH * 8 + nf8;
    size_t wrow = (size_t)(nf * 16 + (lane & 15)) * DIM + ko;
    const __bf16* bh = W1T_hi + wrow;
    const __bf16* bl = W1T_lo + wrow;
#pragma unroll
    for (int ks = 0; ks < 4; ++ks) {
      bf16x8 wh = *(const bf16x8*)(bh + ks * 32);
      bf16x8 wl = *(const bf16x8*)(bl + ks * 32);
      acc[nf8] = mfma16(a_hi[ks], wh, acc[nf8]);
      acc[nf8] = mfma16(a_lo[ks], wh, acc[nf8]);
      acc[nf8] = mfma16(a_hi[ks], wl, acc[nf8]);
    }
  }
  int c0 = lane & 15;
  int rr = rbase + (lane >> 4) * 4;
  int rep = blockIdx.x & 7;
#pragma unroll
  for (int nf8 = 0; nf8 < 8; ++nf8) {
    int c = (colH * 8 + nf8) * 16 + c0;
    float bias = b1[c];
    float s = 0.f, q = 0.f;
#pragma unroll
    for (int j = 0; j < 4; ++j) {
      float v = acc[nf8][j] + bias;
      __bf16 hi = (__bf16)v;
      y1h[(size_t)(rr + j) * TWO_D + c] = hi;
      y1l[(size_t)(rr + j) * TWO_D + c] = (__bf16)(v - (float)hi);
      s += v; q += v * v;
    }
    s += __shfl_xor(s, 16); s += __shfl_xor(s, 32);
    q += __shfl_xor(q, 16); q += __shfl_xor(q, 32);
    if (lane < 16) {
      atomicAdd(&s1[rep * TWO_D + c], s);
      atomicAdd(&q1[rep * TWO_D + c], q);
    }
  }
}

// ---------------- GEMM2: prologue computes BN1 scale/shift from stats ----------------
__global__ __launch_bounds__(256) void k_gemm2(const __bf16* __restrict__ y1h,
    const __bf16* __restrict__ y1l,
    const __bf16* __restrict__ W2T_hi, const __bf16* __restrict__ W2T_lo,
    const float* __restrict__ b2,
    const float* __restrict__ s1, const float* __restrict__ q1,
    const float* __restrict__ bn1g, const float* __restrict__ bn1b,
    float* __restrict__ y2, float* __restrict__ s2, float* __restrict__ q2) {
  __shared__ float sc1s[TWO_D], sh1s[TWO_D];
  int tid = threadIdx.x;
  {
    int c = tid;
    float s = 0.f, q = 0.f;
#pragma unroll
    for (int rep = 0; rep < 8; ++rep) { s += s1[rep * TWO_D + c]; q += q1[rep * TWO_D + c]; }
    float m = s * (1.f / N_NODES);
    float var = q * (1.f / N_NODES) - m * m;
    float a = bn1g[c] / sqrtf(var + 1e-5f);
    sc1s[c] = a; sh1s[c] = bn1b[c] - m * a;
  }
  __syncthreads();
  int lane = tid & 63, wid = tid >> 6;
  int rowH = wid >> 1, colH = wid & 1;
  int rbase = blockIdx.x * 32 + rowH * 16;
  int r = rbase + (lane & 15);
  int ko = (lane >> 4) * 8;
  bf16x8 a_hi[8], a_lo[8];
#pragma unroll
  for (int ks = 0; ks < 8; ++ks) {
    int kb = ks * 32 + ko;
    bf16x8 rh = *(const bf16x8*)(y1h + (size_t)r * TWO_D + kb);
    bf16x8 rl = *(const bf16x8*)(y1l + (size_t)r * TWO_D + kb);
    f32x4 sc0 = *(const f32x4*)(&sc1s[kb]);
    f32x4 sc1 = *(const f32x4*)(&sc1s[kb + 4]);
    f32x4 sh0 = *(const f32x4*)(&sh1s[kb]);
    f32x4 sh1 = *(const f32x4*)(&sh1s[kb + 4]);
    bf16x8 th, tl;
#pragma unroll
    for (int j = 0; j < 4; ++j) {
      float r0 = (float)rh[j] + (float)rl[j];
      float r1 = (float)rh[4 + j] + (float)rl[4 + j];
      float v0 = fmaxf(r0 * sc0[j] + sh0[j], 0.f);
      float v1 = fmaxf(r1 * sc1[j] + sh1[j], 0.f);
      th[j] = (__bf16)v0;     tl[j] = (__bf16)(v0 - (float)th[j]);
      th[4+j] = (__bf16)v1;   tl[4+j] = (__bf16)(v1 - (float)th[4+j]);
    }
    a_hi[ks] = th; a_lo[ks] = tl;
  }
  const f32x4 fz = {0.f, 0.f, 0.f, 0.f};
  f32x4 acc[4];
#pragma unroll
  for (int nf4 = 0; nf4 < 4; ++nf4) acc[nf4] = fz;
#pragma unroll
  for (int nf4 = 0; nf4 < 4; ++nf4) {
    int nf = colH * 4 + nf4;
    size_t wrow = (size_t)(nf * 16 + (lane & 15)) * TWO_D + ko;
    const __bf16* bh = W2T_hi + wrow;
    const __bf16* bl = W2T_lo + wrow;
#pragma unroll
    for (int ks = 0; ks < 8; ++ks) {
      bf16x8 wh = *(const bf16x8*)(bh + ks * 32);
      bf16x8 wl = *(const bf16x8*)(bl + ks * 32);
      acc[nf4] = mfma16(a_hi[ks], wh, acc[nf4]);
      acc[nf4] = mfma16(a_lo[ks], wh, acc[nf4]);
      acc[nf4] = mfma16(a_hi[ks], wl, acc[nf4]);
    }
  }
  int c0 = lane & 15;
  int rr = rbase + (lane >> 4) * 4;
  int rep = blockIdx.x & 7;
#pragma unroll
  for (int nf4 = 0; nf4 < 4; ++nf4) {
    int c = (colH * 4 + nf4) * 16 + c0;
    float bias = b2[c];
    float s = 0.f, q = 0.f;
#pragma unroll
    for (int j = 0; j < 4; ++j) {
      float v = acc[nf4][j] + bias;
      y2[(size_t)(rr + j) * DIM + c] = v;
      s += v; q += v * v;
    }
    s += __shfl_xor(s, 16); s += __shfl_xor(s, 32);
    q += __shfl_xor(q, 16); q += __shfl_xor(q, 32);
    if (lane < 16) {
      atomicAdd(&s2[rep * DIM + c], s);
      atomicAdd(&q2[rep * DIM + c], q);
    }
  }
}

// ---------------- fused virtual-node GEMM1 (+ col stats) ----------------
__global__ __launch_bounds__(256) void k_vgemm1(const float* __restrict__ pooled,
    const float* __restrict__ W1, const float* __restrict__ b1,
    float* __restrict__ tv, float* __restrict__ sv1, float* __restrict__ qv1) {
  __shared__ float row[DIM];
  int g = blockIdx.x, tid = threadIdx.x;
  if (tid < DIM) row[tid] = pooled[g * DIM + tid];
  __syncthreads();
  int c = tid;
  float acc = b1[c];
  for (int k = 0; k < DIM; ++k) acc = fmaf(row[k], W1[k * TWO_D + c], acc);
  tv[g * TWO_D + c] = acc;
  int rep = g & 7;
  atomicAdd(&sv1[rep * TWO_D + c], acc);
  atomicAdd(&qv1[rep * TWO_D + c], acc * acc);
}

// ---------------- fused virtual-node BN1+relu+GEMM2 (+ col stats) ----------------
__global__ __launch_bounds__(256) void k_vgemm2(const float* __restrict__ tv,
    const float* __restrict__ sv1, const float* __restrict__ qv1,
    const float* __restrict__ bn1g, const float* __restrict__ bn1b,
    const float* __restrict__ W2, const float* __restrict__ b2,
    float* __restrict__ vnr, float* __restrict__ sv2, float* __restrict__ qv2) {
  __shared__ float trow[TWO_D];
  int g = blockIdx.x, tid = threadIdx.x;
  {
    float s = 0.f, q = 0.f;
#pragma unroll
    for (int rep = 0; rep < 8; ++rep) { s += sv1[rep * TWO_D + tid]; q += qv1[rep * TWO_D + tid]; }
    float m = s * (1.f / NGRAPH);
    float var = q * (1.f / NGRAPH) - m * m;
    float a = bn1g[tid] / sqrtf(var + 1e-5f);
    trow[tid] = fmaxf(tv[g * TWO_D + tid] * a + (bn1b[tid] - m * a), 0.f);
  }
  __syncthreads();
  if (tid < DIM) {
    float acc = b2[tid];
    for (int k = 0; k < TWO_D; ++k) acc = fmaf(trow[k], W2[k * DIM + tid], acc);
    vnr[g * DIM + tid] = acc;
    int rep = g & 7;
    atomicAdd(&sv2[rep * DIM + tid], acc);
    atomicAdd(&qv2[rep * DIM + tid], acc * acc);
  }
}

// ---------------- fused BN2 finalize + relu + vn(BN2+relu) gather -> h_hi/h_lo ----------------
__global__ __launch_bounds__(256) void k_bn2hin(const float* __restrict__ y2,
    const float* __restrict__ s2, const float* __restrict__ q2,
    const float* __restrict__ bng, const float* __restrict__ bnb,
    const float* __restrict__ vnr, const float* __restrict__ sv2,
    const float* __restrict__ qv2, const float* __restrict__ vbn2g,
    const float* __restrict__ vbn2b, const int* __restrict__ batch,
    __bf16* __restrict__ h_hi, __bf16* __restrict__ h_lo) {
  __shared__ float sc2s[DIM], sh2s[DIM], scvn[DIM], shvn[DIM];
  int tid = threadIdx.x;
  if (tid < DIM) {
    float s = 0.f, q = 0.f;
#pragma unroll
    for (int rep = 0; rep < 8; ++rep) { s += s2[rep * DIM + tid]; q += q2[rep * DIM + tid]; }
    float m = s * (1.f / N_NODES);
    float var = q * (1.f / N_NODES) - m * m;
    float a = bng[tid] / sqrtf(var + 1e-5f);
    sc2s[tid] = a; sh2s[tid] = bnb[tid] - m * a;
    float sv = 0.f, qv = 0.f;
#pragma unroll
    for (int rep = 0; rep < 8; ++rep) { sv += sv2[rep * DIM + tid]; qv += qv2[rep * DIM + tid]; }
    float mv = sv * (1.f / NGRAPH);
    float varv = qv * (1.f / NGRAPH) - mv * mv;
    float av = vbn2g[tid] / sqrtf(varv + 1e-5f);
    scvn[tid] = av; shvn[tid] = vbn2b[tid] - mv * av;
  }
  __syncthreads();
  int idx = blockIdx.x * 256 + tid;
  if (idx >= N_NODES * (DIM / 4)) return;
  int c4 = idx & 31;
  int row = idx >> 5;
  f32x4 y = ((const f32x4*)y2)[idx];
  f32x4 scv = ((const f32x4*)sc2s)[c4];
  f32x4 shv = ((const f32x4*)sh2s)[c4];
  f32x4 vsc = ((const f32x4*)scvn)[c4];
  f32x4 vsh = ((const f32x4*)shvn)[c4];
  int b = batch[row];
  f32x4 vr = ((const f32x4*)vnr)[b * 32 + c4];
  bf16x4 oh, ol;
#pragma unroll
  for (int j = 0; j < 4; ++j) {
    float vnv = fmaxf(vr[j] * vsc[j] + vsh[j], 0.f);
    float o = fmaxf(y[j] * scv[j] + shv[j], 0.f) + vnv;
    __bf16 hi = (__bf16)o;
    oh[j] = hi;
    ol[j] = (__bf16)(o - (float)hi);
  }
  ((bf16x4*)h_hi)[idx] = oh;
  ((bf16x4*)h_lo)[idx] = ol;
}

__global__ __launch_bounds__(256) void k_out(const float* __restrict__ y2,
    const float* __restrict__ s2, const float* __restrict__ q2,
    const float* __restrict__ bng, const float* __restrict__ bnb,
    float* __restrict__ out) {
  __shared__ float sc2s[DIM], sh2s[DIM];
  int tid = threadIdx.x;
  if (tid < DIM) {
    float s = 0.f, q = 0.f;
#pragma unroll
    for (int rep = 0; rep < 8; ++rep) { s += s2[rep * DIM + tid]; q += q2[rep * DIM + tid]; }
    float m = s * (1.f / N_NODES);
    float var = q * (1.f / N_NODES) - m * m;
    float a = bng[tid] / sqrtf(var + 1e-5f);
    sc2s[tid] = a; sh2s[tid] = bnb[tid] - m * a;
  }
  __syncthreads();
  int idx = blockIdx.x * 256 + tid;
  if (idx >= N_NODES * (DIM / 4)) return;
  int c4 = idx & 31;
  f32x4 y = ((const f32x4*)y2)[idx];
  f32x4 scv = ((const f32x4*)sc2s)[c4];
  f32x4 shv = ((const f32x4*)sh2s)[c4];
  f32x4 o;
#pragma unroll
  for (int j = 0; j < 4; ++j) o[j] = y[j] * scv[j] + shv[j];
  ((f32x4*)out)[idx] = o;
}

// ---------------- host ----------------
extern "C" void kernel_launch(void* const* d_in, const int* in_sizes, int n_in,
                              void* d_out, int out_size, void* d_ws, size_t ws_size,
                              hipStream_t stream) {
  const float* x         = (const float*)d_in[0];
  const float* edge_attr = (const float*)d_in[1];
  const int*   edge_index= (const int*)d_in[2];
  const int*   batch     = (const int*)d_in[3];
  const float* enc_W     = (const float*)d_in[4];
  const float* enc_b     = (const float*)d_in[5];
  const float* vn_emb    = (const float*)d_in[6];
  const float* eps       = (const float*)d_in[7];
  const float* edge_W    = (const float*)d_in[8];
  const float* edge_b    = (const float*)d_in[9];
  const float* mlp_W1    = (const float*)d_in[10];
  const float* mlp_b1    = (const float*)d_in[11];
  const float* mlp_bn1_g = (const float*)d_in[12];
  const float* mlp_bn1_b = (const float*)d_in[13];
  const float* mlp_W2    = (const float*)d_in[14];
  const float* mlp_b2    = (const float*)d_in[15];
  const float* bn_g      = (const float*)d_in[16];
  const float* bn_b      = (const float*)d_in[17];
  const float* vn_W1     = (const float*)d_in[18];
  const float* vn_b1     = (const float*)d_in[19];
  const float* vn_bn1_g  = (const float*)d_in[20];
  const float* vn_bn1_b  = (const float*)d_in[21];
  const float* vn_W2     = (const float*)d_in[22];
  const float* vn_b2     = (const float*)d_in[23];
  const float* vn_bn2_g  = (const float*)d_in[24];
  const float* vn_bn2_b  = (const float*)d_in[25];

  char* wsb = (char*)d_ws;
  size_t off = 0;
  auto take = [&](size_t bytes) -> void* {
    void* p = wsb + off;
    off += (bytes + 255) & ~(size_t)255;
    return p;
  };
  int*    counts  = (int*)take((size_t)2 * N_NODES * 4);
  int*    cursor  = counts + N_NODES;
  float*  stats   = (float*)take((size_t)NLAYER * 12288 * 4);
  size_t  memset_bytes = (size_t)2 * N_NODES * 4 + (size_t)NLAYER * 12288 * 4;
  __bf16* h_hi    = (__bf16*)take((size_t)N_NODES * DIM * 2);
  __bf16* h_lo    = (__bf16*)take((size_t)N_NODES * DIM * 2);
  float*  y2      = (float*)take((size_t)N_NODES * DIM * 4);
  __bf16* y1h     = (__bf16*)take((size_t)N_NODES * TWO_D * 2);
  __bf16* y1l     = (__bf16*)take((size_t)N_NODES * TWO_D * 2);
  __bf16* z_hi    = (__bf16*)take((size_t)N_NODES * DIM * 2);
  __bf16* z_lo    = (__bf16*)take((size_t)N_NODES * DIM * 2);
  int*    csr_src = (int*)take((size_t)N_EDGES * 4);
  __bf16* ea_csr  = (__bf16*)take((size_t)N_EDGES * 8 * 2);
  int*    perm    = (int*)take((size_t)N_EDGES * 4);
  int*    offsets = (int*)take((size_t)(N_NODES + 1) * 4);
  int*    slocal  = (int*)take((size_t)(N_NODES + 1024) * 4);
  int*    sbsum   = (int*)take(64 * 4);
  int*    scarry  = sbsum + 32;
  int*    gs      = (int*)take((size_t)(NGRAPH + 1) * 4);
  float*  pooled  = (float*)take((size_t)NGRAPH * DIM * 4);
  float*  tv      = (float*)take((size_t)NGRAPH * TWO_D * 4);
  float*  vnr     = (float*)take((size_t)NGRAPH * DIM * 4);
  float*  vn0     = (float*)take((size_t)NGRAPH * DIM * 4);
  __bf16* encT_hi = (__bf16*)take((size_t)DIM * DIM * 2);
  __bf16* encT_lo = (__bf16*)take((size_t)DIM * DIM * 2);
  __bf16* W1T_hi  = (__bf16*)take((size_t)NLAYER * DIM * TWO_D * 2);
  __bf16* W1T_lo  = (__bf16*)take((size_t)NLAYER * DIM * TWO_D * 2);
  __bf16* W2T_hi  = (__bf16*)take((size_t)NLAYER * TWO_D * DIM * 2);
  __bf16* W2T_lo  = (__bf16*)take((size_t)NLAYER * TWO_D * DIM * 2);
  if (off > ws_size) return;

  const int* srcArr = edge_index;
  const int* dstArr = edge_index + N_EDGES;

  hipMemsetAsync(counts, 0, memset_bytes, stream);

  k_hist<<<N_EDGES / 256, 256, 0, stream>>>(dstArr, counts);
  k_scanA<<<20, 1024, 0, stream>>>(counts, slocal, sbsum);
  k_scanB<<<1, 256, 0, stream>>>(sbsum, scarry, offsets, batch, gs);
  k_scanC<<<20, 1024, 0, stream>>>(slocal, scarry, offsets);
  k_fillA<<<N_EDGES / 256, 256, 0, stream>>>(dstArr, offsets, cursor, perm);
  k_fillB<<<N_EDGES / 256, 256, 0, stream>>>(perm, srcArr, edge_attr, csr_src, ea_csr);
  k_convAll<<<336, 1024, 0, stream>>>(enc_W, mlp_W1, mlp_W2,
      encT_hi, encT_lo, W1T_hi, W1T_lo, W2T_hi, W2T_lo);
  k_vninit<<<(NGRAPH * DIM) / 256, 256, 0, stream>>>(vn_emb, vn0);
  k_enc<<<N_NODES / 32, 128, 0, stream>>>(x, encT_hi, encT_lo, enc_b, vn_emb, h_hi, h_lo);

  for (int l = 0; l < NLAYER; ++l) {
    float* s1  = stats + (size_t)l * 12288;
    float* q1  = s1 + 2048;
    float* s2  = s1 + 4096;
    float* q2  = s1 + 5120;
    float* sv1 = s1 + 6144;
    float* qv1 = s1 + 8192;
    float* sv2 = s1 + 10240;
    float* qv2 = s1 + 11264;
    if (l < NLAYER - 1) {
      if (l == 0)
        k_pool<<<NGRAPH, 1024, 0, stream>>>(h_hi, gs, vn0, vn0, nullptr, nullptr,
            nullptr, nullptr, 0, pooled);
      else {
        float* psv2 = stats + (size_t)(l - 1) * 12288 + 10240;
        float* pqv2 = stats + (size_t)(l - 1) * 12288 + 11264;
        k_pool<<<NGRAPH, 1024, 0, stream>>>(h_hi, gs, vn0, vnr, psv2, pqv2,
            vn_bn2_g + (size_t)(l - 1) * DIM, vn_bn2_b + (size_t)(l - 1) * DIM, 1, pooled);
      }
    }
    k_agg<<<N_NODES / 8, 256, 0, stream>>>(h_hi, h_lo, offsets, csr_src, ea_csr,
        edge_W + (size_t)l * EDIM * DIM, edge_b + (size_t)l * DIM, eps, l, z_hi, z_lo);
    k_gemm1<<<N_NODES / 32, 256, 0, stream>>>(z_hi, z_lo,
        W1T_hi + (size_t)l * DIM * TWO_D, W1T_lo + (size_t)l * DIM * TWO_D,
        mlp_b1 + (size_t)l * TWO_D, y1h, y1l, s1, q1);
    k_gemm2<<<N_NODES / 32, 256, 0, stream>>>(y1h, y1l,
        W2T_hi + (size_t)l * TWO_D * DIM, W2T_lo + (size_t)l * TWO_D * DIM,
        mlp_b2 + (size_t)l * DIM, s1, q1,
        mlp_bn1_g + (size_t)l * TWO_D, mlp_bn1_b + (size_t)l * TWO_D,
        y2, s2, q2);
    if (l < NLAYER - 1) {
      k_vgemm1<<<NGRAPH, 256, 0, stream>>>(pooled, vn_W1 + (size_t)l * DIM * TWO_D,
          vn_b1 + (size_t)l * TWO_D, tv, sv1, qv1);
      k_vgemm2<<<NGRAPH, 256, 0, stream>>>(tv, sv1, qv1,
          vn_bn1_g + (size_t)l * TWO_D, vn_bn1_b + (size_t)l * TWO_D,
          vn_W2 + (size_t)l * TWO_D * DIM, vn_b2 + (size_t)l * DIM,
          vnr, sv2, qv2);
      k_bn2hin<<<(N_NODES * 32) / 256, 256, 0, stream>>>(y2, s2, q2,
          bn_g + (size_t)l * DIM, bn_b + (size_t)l * DIM,
          vnr, sv2, qv2, vn_bn2_g + (size_t)l * DIM, vn_bn2_b + (size_t)l * DIM,
          batch, h_hi, h_lo);
    } else {
      k_out<<<(N_NODES * 32) / 256, 256, 0, stream>>>(y2, s2, q2,
          bn_g + (size_t)l * DIM, bn_b + (size_t)l * DIM, (float*)d_out);
    }
  }
}

// Round 14
// 771.606 us; speedup vs baseline: 1.3014x; 1.0182x over previous
//
#include <hip/hip_runtime.h>

#define N_NODES 20000
#define N_EDGES 640000
#define DIM 128
#define NGRAPH 128
#define NLAYER 5
#define EDIM 7
#define TWO_D 256

typedef __bf16 bf16x8 __attribute__((ext_vector_type(8)));
typedef __bf16 bf16x4 __attribute__((ext_vector_type(4)));
typedef __bf16 bf16x2 __attribute__((ext_vector_type(2)));
typedef float  f32x4  __attribute__((ext_vector_type(4)));

__device__ __forceinline__ f32x4 mfma16(bf16x8 a, bf16x8 b, f32x4 c) {
  return __builtin_amdgcn_mfma_f32_16x16x32_bf16(a, b, c, 0, 0, 0);
}

// ---------------- CSR build ----------------
__global__ void k_hist(const int* __restrict__ dst, int* __restrict__ counts) {
  int e = blockIdx.x * blockDim.x + threadIdx.x;
  if (e < N_EDGES) atomicAdd(&counts[dst[e]], 1);
}

__global__ __launch_bounds__(1024) void k_scanA(const int* __restrict__ counts,
    int* __restrict__ local, int* __restrict__ bsum) {
  __shared__ int sd[1024];
  int b = blockIdx.x, tid = threadIdx.x;
  int i = b * 1024 + tid;
  int v = (i < N_NODES) ? counts[i] : 0;
  sd[tid] = v;
  __syncthreads();
  for (int ofs = 1; ofs < 1024; ofs <<= 1) {
    int t = (tid >= ofs) ? sd[tid - ofs] : 0;
    __syncthreads();
    sd[tid] += t;
    __syncthreads();
  }
  if (i <= N_NODES) local[i] = sd[tid] - v;  // exclusive
  if (tid == 1023) bsum[b] = sd[1023];
}

// carry pass + graph-segment starts
__global__ void k_scanB(int* __restrict__ bsum, int* __restrict__ carry,
                        int* __restrict__ offsets, const int* __restrict__ batch,
                        int* __restrict__ gs) {
  int tid = threadIdx.x;
  if (tid == 0) {
    int run = 0;
    for (int b = 0; b < 20; ++b) { carry[b] = run; run += bsum[b]; }
    offsets[N_NODES] = run;
  }
  if (tid <= NGRAPH) {
    if (tid == NGRAPH) gs[NGRAPH] = N_NODES;
    else {
      int lo = 0, hi = N_NODES;
      while (lo < hi) { int mid = (lo + hi) >> 1; if (batch[mid] < tid) lo = mid + 1; else hi = mid; }
      gs[tid] = lo;
    }
  }
}

__global__ __launch_bounds__(1024) void k_scanC(const int* __restrict__ local,
    const int* __restrict__ carry, int* __restrict__ offsets) {
  int i = blockIdx.x * 1024 + threadIdx.x;
  if (i < N_NODES) offsets[i] = local[i] + carry[i >> 10];
}

// fill pass A: only the unavoidable random write (4B perm scatter)
__global__ void k_fillA(const int* __restrict__ dstArr, const int* __restrict__ offsets,
                        int* __restrict__ cursor, int* __restrict__ perm) {
  int e = blockIdx.x * blockDim.x + threadIdx.x;
  if (e >= N_EDGES) return;
  int d = dstArr[e];
  int p = offsets[d] + atomicAdd(&cursor[d], 1);
  perm[p] = e;
}

// fill pass B: coalesced over CSR slots; random READS, sequential writes
__global__ void k_fillB(const int* __restrict__ perm, const int* __restrict__ srcArr,
                        const float* __restrict__ edge_attr,
                        int* __restrict__ csr_src, __bf16* __restrict__ ea_csr) {
  int i = blockIdx.x * blockDim.x + threadIdx.x;
  if (i >= N_EDGES) return;
  int e = perm[i];
  csr_src[i] = srcArr[e];
  const float* ea = edge_attr + (size_t)e * EDIM;
  bf16x8 v;
#pragma unroll
  for (int k = 0; k < EDIM; ++k) v[k] = (__bf16)ea[k];
  v[7] = (__bf16)0.f;
  *(bf16x8*)(ea_csr + (size_t)i * 8) = v;
}

// ---------------- all weight transposes (hi/lo split) in one launch ----------------
__global__ void k_convAll(const float* __restrict__ encW, const float* __restrict__ W1,
    const float* __restrict__ W2,
    __bf16* __restrict__ encT_hi, __bf16* __restrict__ encT_lo,
    __bf16* __restrict__ W1T_hi, __bf16* __restrict__ W1T_lo,
    __bf16* __restrict__ W2T_hi, __bf16* __restrict__ W2T_lo) {
  const int t1 = DIM * DIM;
  const int t2 = NLAYER * DIM * TWO_D;
  const int total = t1 + t2 + t2;
  for (int i = blockIdx.x * blockDim.x + threadIdx.x; i < total;
       i += gridDim.x * blockDim.x) {
    const float* src; __bf16 *dh, *dl; int K, C, idx;
    if (i < t1)            { src = encW; dh = encT_hi; dl = encT_lo; K = DIM;   C = DIM;   idx = i; }
    else if (i < t1 + t2)  { src = W1;   dh = W1T_hi;  dl = W1T_lo;  K = DIM;   C = TWO_D; idx = i - t1; }
    else                   { src = W2;   dh = W2T_hi;  dl = W2T_lo;  K = TWO_D; C = DIM;   idx = i - t1 - t2; }
    int l = idx / (K * C);
    int rem = idx - l * K * C;
    int k = rem / C;
    int c = rem - k * C;
    float v = src[idx];
    __bf16 hi = (__bf16)v;
    __bf16 lo = (__bf16)(v - (float)hi);
    size_t o = (size_t)l * K * C + (size_t)c * K + k;
    dh[o] = hi;
    dl[o] = lo;
  }
}

__global__ void k_vninit(const float* __restrict__ vn_emb, float* __restrict__ vn) {
  int i = blockIdx.x * blockDim.x + threadIdx.x;
  if (i < NGRAPH * DIM) vn[i] = vn_emb[i & (DIM - 1)];
}

// ---------------- encoder GEMM: h = x @ encW + enc_b + vn_emb (hi/lo out) ----------------
__global__ __launch_bounds__(128) void k_enc(const float* __restrict__ x,
    const __bf16* __restrict__ encT_hi, const __bf16* __restrict__ encT_lo,
    const float* __restrict__ enc_b, const float* __restrict__ vn_emb,
    __bf16* __restrict__ h_hi, __bf16* __restrict__ h_lo) {
  int lane = threadIdx.x & 63, wid = threadIdx.x >> 6;
  int rbase = blockIdx.x * 32 + wid * 16;
  int r = rbase + (lane & 15);
  int ko = (lane >> 4) * 8;
  const float* xr = x + (size_t)r * DIM;
  bf16x8 a_hi[4], a_lo[4];
#pragma unroll
  for (int ks = 0; ks < 4; ++ks) {
    f32x4 v0 = *(const f32x4*)(xr + ks * 32 + ko);
    f32x4 v1 = *(const f32x4*)(xr + ks * 32 + ko + 4);
    bf16x8 th, tl;
#pragma unroll
    for (int j = 0; j < 4; ++j) {
      th[j] = (__bf16)v0[j];     tl[j] = (__bf16)(v0[j] - (float)th[j]);
      th[4+j] = (__bf16)v1[j];   tl[4+j] = (__bf16)(v1[j] - (float)th[4+j]);
    }
    a_hi[ks] = th; a_lo[ks] = tl;
  }
  const f32x4 fz = {0.f, 0.f, 0.f, 0.f};
  f32x4 acc[8];
#pragma unroll
  for (int nf = 0; nf < 8; ++nf) acc[nf] = fz;
#pragma unroll
  for (int nf = 0; nf < 8; ++nf) {
    size_t wrow = (size_t)(nf * 16 + (lane & 15)) * DIM + ko;
    const __bf16* bh = encT_hi + wrow;
    const __bf16* bl = encT_lo + wrow;
#pragma unroll
    for (int ks = 0; ks < 4; ++ks) {
      bf16x8 wh = *(const bf16x8*)(bh + ks * 32);
      bf16x8 wl = *(const bf16x8*)(bl + ks * 32);
      acc[nf] = mfma16(a_hi[ks], wh, acc[nf]);
      acc[nf] = mfma16(a_lo[ks], wh, acc[nf]);
      acc[nf] = mfma16(a_hi[ks], wl, acc[nf]);
    }
  }
  int c0 = lane & 15;
  int rr = rbase + (lane >> 4) * 4;
#pragma unroll
  for (int nf = 0; nf < 8; ++nf) {
    int c = nf * 16 + c0;
    float bias = enc_b[c] + vn_emb[c];
#pragma unroll
    for (int j = 0; j < 4; ++j) {
      float v = acc[nf][j] + bias;
      __bf16 hi = (__bf16)v;
      h_hi[(size_t)(rr + j) * DIM + c] = hi;
      h_lo[(size_t)(rr + j) * DIM + c] = (__bf16)(v - (float)hi);
    }
  }
}

// ---------------- per-graph pool: pooled = segsum(h_hi) + vn ----------------
__global__ __launch_bounds__(1024) void k_pool(const __bf16* __restrict__ h_hi,
    const int* __restrict__ gs, const float* __restrict__ vnbuf,
    const float* __restrict__ vnr, const float* __restrict__ sv2,
    const float* __restrict__ qv2, const float* __restrict__ bn2g,
    const float* __restrict__ bn2b, int use_stats,
    float* __restrict__ pooled) {
  __shared__ float red[8][DIM];
  __shared__ float vns[DIM];
  int tid = threadIdx.x;
  int g = blockIdx.x;
  if (tid < DIM) {
    if (use_stats) {
      float s = 0.f, q = 0.f;
#pragma unroll
      for (int rep = 0; rep < 8; ++rep) { s += sv2[rep * DIM + tid]; q += qv2[rep * DIM + tid]; }
      float m = s * (1.f / NGRAPH);
      float var = q * (1.f / NGRAPH) - m * m;
      float a = bn2g[tid] / sqrtf(var + 1e-5f);
      vns[tid] = fmaxf(vnr[g * DIM + tid] * a + (bn2b[tid] - m * a), 0.f);
    } else {
      vns[tid] = vnbuf[g * DIM + tid];
    }
  }
  __syncthreads();
  int d = tid & 127, slot = tid >> 7;
  int lo = gs[g], hi = gs[g + 1];
  float acc = 0.f;
  for (int n = lo + slot; n < hi; n += 8)
    acc += (float)h_hi[(size_t)n * DIM + d];
  red[slot][d] = acc;
  __syncthreads();
  if (slot == 0) {
    float t = vns[d];
#pragma unroll
    for (int s2 = 0; s2 < 8; ++s2) t += red[s2][d];
    pooled[g * DIM + d] = t;
  }
}

// ---------------- GIN aggregation -> z (hi/lo split) ----------------
// Wave-per-node (4 waves/block, grid N/4), 2 ch/lane. Software-pipelined
// batches of 4 edges: src indices one batch ahead (SMEM), h-gathers +
// edge-attr one batch ahead (VMEM/SMEM) -> latency hides under the ~80
// VALU ops of the current batch. Ping-pong A/B register sets (no copies).
__global__ __launch_bounds__(256) void k_agg(const __bf16* __restrict__ h_hi,
    const __bf16* __restrict__ h_lo, const int* __restrict__ offsets,
    const int* __restrict__ csr_src, const __bf16* __restrict__ ea_csr,
    const float* __restrict__ eW, const float* __restrict__ eB,
    const float* __restrict__ eps, int l,
    __bf16* __restrict__ z_hi, __bf16* __restrict__ z_lo) {
  int tid = threadIdx.x;
  int lane = tid & 63, w = tid >> 6;
  int l2 = lane * 2;
  int n = blockIdx.x * 4 + w;
  float w0[EDIM], w1[EDIM];
#pragma unroll
  for (int k = 0; k < EDIM; ++k) {
    float2 wv = *(const float2*)(eW + k * DIM + l2);
    w0[k] = wv.x; w1[k] = wv.y;
  }
  float2 ebv = *(const float2*)(eB + l2);
  int off = offsets[n], end = offsets[n + 1];
  float acc0 = 0.f, acc1 = 0.f;

  auto comp = [&](unsigned hv, unsigned u0, unsigned u1, unsigned u2, unsigned u3) {
    float e0 = __builtin_bit_cast(float, u0 << 16);
    float e1 = __builtin_bit_cast(float, u0 & 0xffff0000u);
    float e2 = __builtin_bit_cast(float, u1 << 16);
    float e3 = __builtin_bit_cast(float, u1 & 0xffff0000u);
    float e4 = __builtin_bit_cast(float, u2 << 16);
    float e5 = __builtin_bit_cast(float, u2 & 0xffff0000u);
    float e6 = __builtin_bit_cast(float, u3 << 16);
    float m0 = __builtin_bit_cast(float, hv << 16) + ebv.x;
    float m1 = __builtin_bit_cast(float, hv & 0xffff0000u) + ebv.y;
    m0 = fmaf(e0, w0[0], m0); m1 = fmaf(e0, w1[0], m1);
    m0 = fmaf(e1, w0[1], m0); m1 = fmaf(e1, w1[1], m1);
    m0 = fmaf(e2, w0[2], m0); m1 = fmaf(e2, w1[2], m1);
    m0 = fmaf(e3, w0[3], m0); m1 = fmaf(e3, w1[3], m1);
    m0 = fmaf(e4, w0[4], m0); m1 = fmaf(e4, w1[4], m1);
    m0 = fmaf(e5, w0[5], m0); m1 = fmaf(e5, w1[5], m1);
    m0 = fmaf(e6, w0[6], m0); m1 = fmaf(e6, w1[6], m1);
    acc0 += fmaxf(m0, 0.f);
    acc1 += fmaxf(m1, 0.f);
  };
  auto loadS = [&](int base, int* s) {
    int iu = __builtin_amdgcn_readfirstlane(base);
#pragma unroll
    for (int t = 0; t < 4; ++t) s[t] = csr_src[iu + t];
  };
  auto loadD = [&](int base, const int* s, unsigned* hv, unsigned* ea) {
    int iu = __builtin_amdgcn_readfirstlane(base);
#pragma unroll
    for (int t = 0; t < 4; ++t) {
      hv[t] = *(const unsigned*)(h_hi + (size_t)s[t] * DIM + l2);
      const unsigned* eu = (const unsigned*)(ea_csr + (size_t)(iu + t) * 8);
#pragma unroll
      for (int k2 = 0; k2 < 4; ++k2) ea[t * 4 + k2] = eu[k2];
    }
  };
  auto compB = [&](const unsigned* hv, const unsigned* ea) {
#pragma unroll
    for (int t = 0; t < 4; ++t)
      comp(hv[t], ea[t * 4], ea[t * 4 + 1], ea[t * 4 + 2], ea[t * 4 + 3]);
  };

  int nb = (end - off) >> 2;
  unsigned hvA[4], eaA[16], hvB[4], eaB[16];
  int sN[4];
  if (nb >= 1) {
    int sp[4];
    loadS(off, sp);
    loadD(off, sp, hvA, eaA);
    if (nb >= 2) loadS(off + 4, sN);
  }
  int b = 0;
  for (; b + 1 < nb; b += 2) {
    loadD(off + (b + 1) * 4, sN, hvB, eaB);        // gathers for b+1 (sN ready)
    if (b + 2 < nb) loadS(off + (b + 2) * 4, sN);  // src for b+2 in flight
    compB(hvA, eaA);                               // compute b
    if (b + 2 < nb) {
      loadD(off + (b + 2) * 4, sN, hvA, eaA);
      if (b + 3 < nb) loadS(off + (b + 3) * 4, sN);
    }
    compB(hvB, eaB);                               // compute b+1
  }
  if (b < nb) compB(hvA, eaA);
  for (int i = off + (nb << 2); i < end; ++i) {
    int iu = __builtin_amdgcn_readfirstlane(i);
    int s = csr_src[iu];
    const unsigned* eu = (const unsigned*)(ea_csr + (size_t)iu * 8);
    unsigned hv = *(const unsigned*)(h_hi + (size_t)s * DIM + l2);
    comp(hv, eu[0], eu[1], eu[2], eu[3]);
  }

  float epsv = 1.f + eps[l];
  unsigned hvh = *(const unsigned*)(h_hi + (size_t)n * DIM + l2);
  unsigned hvl = *(const unsigned*)(h_lo + (size_t)n * DIM + l2);
  float s0 = __builtin_bit_cast(float, hvh << 16) + __builtin_bit_cast(float, hvl << 16);
  float s1 = __builtin_bit_cast(float, hvh & 0xffff0000u) + __builtin_bit_cast(float, hvl & 0xffff0000u);
  float v0 = epsv * s0 + acc0;
  float v1 = epsv * s1 + acc1;
  __bf16 hi0 = (__bf16)v0, hi1 = (__bf16)v1;
  bf16x2 zh; zh[0] = hi0; zh[1] = hi1;
  bf16x2 zl; zl[0] = (__bf16)(v0 - (float)hi0); zl[1] = (__bf16)(v1 - (float)hi1);
  *(bf16x2*)(z_hi + (size_t)n * DIM + l2) = zh;
  *(bf16x2*)(z_lo + (size_t)n * DIM + l2) = zl;
}

// ---------------- GEMM1: y1 = z @ W1 + b1 (+ BN1 stats), y1 bf16 hi/lo ----------------
__global__ __launch_bounds__(256) void k_gemm1(const __bf16* __restrict__ z_hi,
    const __bf16* __restrict__ z_lo,
    const __bf16* __restrict__ W1T_hi, const __bf16* __restrict__ W1T_lo,
    const float* __restrict__ b1,
    __bf16* __restrict__ y1h, __bf16* __restrict__ y1l,
    float* __restrict__ s1, float* __restrict__ q1) {
  int tid = threadIdx.x;
  int lane = tid & 63, wid = tid >> 6;
  int rowH = wid >> 1, colH = wid & 1;
  int rbase = blockIdx.x * 32 + rowH * 16;
  int r = rbase + (lane & 15);
  int ko = (lane >> 4) * 8;
  bf16x8 a_hi[4], a_lo[4];
#pragma unroll
  for (int ks = 0; ks < 4; ++ks) {
    a_hi[ks] = *(const bf16x8*)(z_hi + (size_t)r * DIM + ks * 32 + ko);
    a_lo[ks] = *(const bf16x8*)(z_lo + (size_t)r * DIM + ks * 32 + ko);
  }
  const f32x4 fz = {0.f, 0.f, 0.f, 0.f};
  f32x4 acc[8];
#pragma unroll
  for (int nf8 = 0; nf8 < 8; ++nf8) acc[nf8] = fz;
#pragma unroll
  for (int nf8 = 0; nf8 < 8; ++nf8) {
    int nf = colH * 8 + nf8;
    size_t wrow = (size_t)(nf * 16 + (lane & 15)) * DIM + ko;
    const __bf16* bh = W1T_hi + wrow;
    const __bf16* bl = W1T_lo + wrow;
#pragma unroll
    for (int ks = 0; ks < 4; ++ks) {
      bf16x8 wh = *(const bf16x8*)(bh + ks * 32);
      bf16x8 wl = *(const bf16x8*)(bl + ks * 32);
      acc[nf8] = mfma16(a_hi[ks], wh, acc[nf8]);
      acc[nf8] = mfma16(a_lo[ks], wh, acc[nf8]);
      acc[nf8] = mfma16(a_hi[ks], wl, acc[nf8]);
    }
  }
  int c0 = lane & 15;
  int rr = rbase + (lane >> 4) * 4;
  int rep = blockIdx.x & 7;
#pragma unroll
  for (int nf8 = 0; nf8 < 8; ++nf8) {
    int c = (colH * 8 + nf8) * 16 + c0;
    float bias = b1[c];
    float s = 0.f, q = 0.f;
#pragma unroll
    for (int j = 0; j < 4; ++j) {
      float v = acc[nf8][j] + bias;
      __bf16 hi = (__bf16)v;
      y1h[(size_t)(rr + j) * TWO_D + c] = hi;
      y1l[(size_t)(rr + j) * TWO_D + c] = (__bf16)(v - (float)hi);
      s += v; q += v * v;
    }
    s += __shfl_xor(s, 16); s += __shfl_xor(s, 32);
    q += __shfl_xor(q, 16); q += __shfl_xor(q, 32);
    if (lane < 16) {
      atomicAdd(&s1[rep * TWO_D + c], s);
      atomicAdd(&q1[rep * TWO_D + c], q);
    }
  }
}

// ---------------- GEMM2: prologue computes BN1 scale/shift from stats ----------------
__global__ __launch_bounds__(256) void k_gemm2(const __bf16* __restrict__ y1h,
    const __bf16* __restrict__ y1l,
    const __bf16* __restrict__ W2T_hi, const __bf16* __restrict__ W2T_lo,
    const float* __restrict__ b2,
    const float* __restrict__ s1, const float* __restrict__ q1,
    const float* __restrict__ bn1g, const float* __restrict__ bn1b,
    float* __restrict__ y2, float* __restrict__ s2, float* __restrict__ q2) {
  __shared__ float sc1s[TWO_D], sh1s[TWO_D];
  int tid = threadIdx.x;
  {
    int c = tid;
    float s = 0.f, q = 0.f;
#pragma unroll
    for (int rep = 0; rep < 8; ++rep) { s += s1[rep * TWO_D + c]; q += q1[rep * TWO_D + c]; }
    float m = s * (1.f / N_NODES);
    float var = q * (1.f / N_NODES) - m * m;
    float a = bn1g[c] / sqrtf(var + 1e-5f);
    sc1s[c] = a; sh1s[c] = bn1b[c] - m * a;
  }
  __syncthreads();
  int lane = tid & 63, wid = tid >> 6;
  int rowH = wid >> 1, colH = wid & 1;
  int rbase = blockIdx.x * 32 + rowH * 16;
  int r = rbase + (lane & 15);
  int ko = (lane >> 4) * 8;
  bf16x8 a_hi[8], a_lo[8];
#pragma unroll
  for (int ks = 0; ks < 8; ++ks) {
    int kb = ks * 32 + ko;
    bf16x8 rh = *(const bf16x8*)(y1h + (size_t)r * TWO_D + kb);
    bf16x8 rl = *(const bf16x8*)(y1l + (size_t)r * TWO_D + kb);
    f32x4 sc0 = *(const f32x4*)(&sc1s[kb]);
    f32x4 sc1 = *(const f32x4*)(&sc1s[kb + 4]);
    f32x4 sh0 = *(const f32x4*)(&sh1s[kb]);
    f32x4 sh1 = *(const f32x4*)(&sh1s[kb + 4]);
    bf16x8 th, tl;
#pragma unroll
    for (int j = 0; j < 4; ++j) {
      float r0 = (float)rh[j] + (float)rl[j];
      float r1 = (float)rh[4 + j] + (float)rl[4 + j];
      float v0 = fmaxf(r0 * sc0[j] + sh0[j], 0.f);
      float v1 = fmaxf(r1 * sc1[j] + sh1[j], 0.f);
      th[j] = (__bf16)v0;     tl[j] = (__bf16)(v0 - (float)th[j]);
      th[4+j] = (__bf16)v1;   tl[4+j] = (__bf16)(v1 - (float)th[4+j]);
    }
    a_hi[ks] = th; a_lo[ks] = tl;
  }
  const f32x4 fz = {0.f, 0.f, 0.f, 0.f};
  f32x4 acc[4];
#pragma unroll
  for (int nf4 = 0; nf4 < 4; ++nf4) acc[nf4] = fz;
#pragma unroll
  for (int nf4 = 0; nf4 < 4; ++nf4) {
    int nf = colH * 4 + nf4;
    size_t wrow = (size_t)(nf * 16 + (lane & 15)) * TWO_D + ko;
    const __bf16* bh = W2T_hi + wrow;
    const __bf16* bl = W2T_lo + wrow;
#pragma unroll
    for (int ks = 0; ks < 8; ++ks) {
      bf16x8 wh = *(const bf16x8*)(bh + ks * 32);
      bf16x8 wl = *(const bf16x8*)(bl + ks * 32);
      acc[nf4] = mfma16(a_hi[ks], wh, acc[nf4]);
      acc[nf4] = mfma16(a_lo[ks], wh, acc[nf4]);
      acc[nf4] = mfma16(a_hi[ks], wl, acc[nf4]);
    }
  }
  int c0 = lane & 15;
  int rr = rbase + (lane >> 4) * 4;
  int rep = blockIdx.x & 7;
#pragma unroll
  for (int nf4 = 0; nf4 < 4; ++nf4) {
    int c = (colH * 4 + nf4) * 16 + c0;
    float bias = b2[c];
    float s = 0.f, q = 0.f;
#pragma unroll
    for (int j = 0; j < 4; ++j) {
      float v = acc[nf4][j] + bias;
      y2[(size_t)(rr + j) * DIM + c] = v;
      s += v; q += v * v;
    }
    s += __shfl_xor(s, 16); s += __shfl_xor(s, 32);
    q += __shfl_xor(q, 16); q += __shfl_xor(q, 32);
    if (lane < 16) {
      atomicAdd(&s2[rep * DIM + c], s);
      atomicAdd(&q2[rep * DIM + c], q);
    }
  }
}

// ---------------- fused virtual-node GEMM1 (+ col stats) ----------------
__global__ __launch_bounds__(256) void k_vgemm1(const float* __restrict__ pooled,
    const float* __restrict__ W1, const float* __restrict__ b1,
    float* __restrict__ tv, float* __restrict__ sv1, float* __restrict__ qv1) {
  __shared__ float row[DIM];
  int g = blockIdx.x, tid = threadIdx.x;
  if (tid < DIM) row[tid] = pooled[g * DIM + tid];
  __syncthreads();
  int c = tid;
  float acc = b1[c];
  for (int k = 0; k < DIM; ++k) acc = fmaf(row[k], W1[k * TWO_D + c], acc);
  tv[g * TWO_D + c] = acc;
  int rep = g & 7;
  atomicAdd(&sv1[rep * TWO_D + c], acc);
  atomicAdd(&qv1[rep * TWO_D + c], acc * acc);
}

// ---------------- fused virtual-node BN1+relu+GEMM2 (+ col stats) ----------------
__global__ __launch_bounds__(256) void k_vgemm2(const float* __restrict__ tv,
    const float* __restrict__ sv1, const float* __restrict__ qv1,
    const float* __restrict__ bn1g, const float* __restrict__ bn1b,
    const float* __restrict__ W2, const float* __restrict__ b2,
    float* __restrict__ vnr, float* __restrict__ sv2, float* __restrict__ qv2) {
  __shared__ float trow[TWO_D];
  int g = blockIdx.x, tid = threadIdx.x;
  {
    float s = 0.f, q = 0.f;
#pragma unroll
    for (int rep = 0; rep < 8; ++rep) { s += sv1[rep * TWO_D + tid]; q += qv1[rep * TWO_D + tid]; }
    float m = s * (1.f / NGRAPH);
    float var = q * (1.f / NGRAPH) - m * m;
    float a = bn1g[tid] / sqrtf(var + 1e-5f);
    trow[tid] = fmaxf(tv[g * TWO_D + tid] * a + (bn1b[tid] - m * a), 0.f);
  }
  __syncthreads();
  if (tid < DIM) {
    float acc = b2[tid];
    for (int k = 0; k < TWO_D; ++k) acc = fmaf(trow[k], W2[k * DIM + tid], acc);
    vnr[g * DIM + tid] = acc;
    int rep = g & 7;
    atomicAdd(&sv2[rep * DIM + tid], acc);
    atomicAdd(&qv2[rep * DIM + tid], acc * acc);
  }
}

// ---------------- fused BN2 finalize + relu + vn(BN2+relu) gather -> h_hi/h_lo ----------------
__global__ __launch_bounds__(256) void k_bn2hin(const float* __restrict__ y2,
    const float* __restrict__ s2, const float* __restrict__ q2,
    const float* __restrict__ bng, const float* __restrict__ bnb,
    const float* __restrict__ vnr, const float* __restrict__ sv2,
    const float* __restrict__ qv2, const float* __restrict__ vbn2g,
    const float* __restrict__ vbn2b, const int* __restrict__ batch,
    __bf16* __restrict__ h_hi, __bf16* __restrict__ h_lo) {
  __shared__ float sc2s[DIM], sh2s[DIM], scvn[DIM], shvn[DIM];
  int tid = threadIdx.x;
  if (tid < DIM) {
    float s = 0.f, q = 0.f;
#pragma unroll
    for (int rep = 0; rep < 8; ++rep) { s += s2[rep * DIM + tid]; q += q2[rep * DIM + tid]; }
    float m = s * (1.f / N_NODES);
    float var = q * (1.f / N_NODES) - m * m;
    float a = bng[tid] / sqrtf(var + 1e-5f);
    sc2s[tid] = a; sh2s[tid] = bnb[tid] - m * a;
    float sv = 0.f, qv = 0.f;
#pragma unroll
    for (int rep = 0; rep < 8; ++rep) { sv += sv2[rep * DIM + tid]; qv += qv2[rep * DIM + tid]; }
    float mv = sv * (1.f / NGRAPH);
    float varv = qv * (1.f / NGRAPH) - mv * mv;
    float av = vbn2g[tid] / sqrtf(varv + 1e-5f);
    scvn[tid] = av; shvn[tid] = vbn2b[tid] - mv * av;
  }
  __syncthreads();
  int idx = blockIdx.x * 256 + tid;
  if (idx >= N_NODES * (DIM / 4)) return;
  int c4 = idx & 31;
  int row = idx >> 5;
  f32x4 y = ((const f32x4*)y2)[idx];
  f32x4 scv = ((const f32x4*)sc2s)[c4];
  f32x4 shv = ((const f32x4*)sh2s)[c4];
  f32x4 vsc = ((const f32x4*)scvn)[c4];
  f32x4 vsh = ((const f32x4*)shvn)[c4];
  int b = batch[row];
  f32x4 vr = ((const f32x4*)vnr)[b * 32 + c4];
  bf16x4 oh, ol;
#pragma unroll
  for (int j = 0; j < 4; ++j) {
    float vnv = fmaxf(vr[j] * vsc[j] + vsh[j], 0.f);
    float o = fmaxf(y[j] * scv[j] + shv[j], 0.f) + vnv;
    __bf16 hi = (__bf16)o;
    oh[j] = hi;
    ol[j] = (__bf16)(o - (float)hi);
  }
  ((bf16x4*)h_hi)[idx] = oh;
  ((bf16x4*)h_lo)[idx] = ol;
}

__global__ __launch_bounds__(256) void k_out(const float* __restrict__ y2,
    const float* __restrict__ s2, const float* __restrict__ q2,
    const float* __restrict__ bng, const float* __restrict__ bnb,
    float* __restrict__ out) {
  __shared__ float sc2s[DIM], sh2s[DIM];
  int tid = threadIdx.x;
  if (tid < DIM) {
    float s = 0.f, q = 0.f;
#pragma unroll
    for (int rep = 0; rep < 8; ++rep) { s += s2[rep * DIM + tid]; q += q2[rep * DIM + tid]; }
    float m = s * (1.f / N_NODES);
    float var = q * (1.f / N_NODES) - m * m;
    float a = bng[tid] / sqrtf(var + 1e-5f);
    sc2s[tid] = a; sh2s[tid] = bnb[tid] - m * a;
  }
  __syncthreads();
  int idx = blockIdx.x * 256 + tid;
  if (idx >= N_NODES * (DIM / 4)) return;
  int c4 = idx & 31;
  f32x4 y = ((const f32x4*)y2)[idx];
  f32x4 scv = ((const f32x4*)sc2s)[c4];
  f32x4 shv = ((const f32x4*)sh2s)[c4];
  f32x4 o;
#pragma unroll
  for (int j = 0; j < 4; ++j) o[j] = y[j] * scv[j] + shv[j];
  ((f32x4*)out)[idx] = o;
}

// ---------------- host ----------------
extern "C" void kernel_launch(void* const* d_in, const int* in_sizes, int n_in,
                              void* d_out, int out_size, void* d_ws, size_t ws_size,
                              hipStream_t stream) {
  const float* x         = (const float*)d_in[0];
  const float* edge_attr = (const float*)d_in[1];
  const int*   edge_index= (const int*)d_in[2];
  const int*   batch     = (const int*)d_in[3];
  const float* enc_W     = (const float*)d_in[4];
  const float* enc_b     = (const float*)d_in[5];
  const float* vn_emb    = (const float*)d_in[6];
  const float* eps       = (const float*)d_in[7];
  const float* edge_W    = (const float*)d_in[8];
  const float* edge_b    = (const float*)d_in[9];
  const float* mlp_W1    = (const float*)d_in[10];
  const float* mlp_b1    = (const float*)d_in[11];
  const float* mlp_bn1_g = (const float*)d_in[12];
  const float* mlp_bn1_b = (const float*)d_in[13];
  const float* mlp_W2    = (const float*)d_in[14];
  const float* mlp_b2    = (const float*)d_in[15];
  const float* bn_g      = (const float*)d_in[16];
  const float* bn_b      = (const float*)d_in[17];
  const float* vn_W1     = (const float*)d_in[18];
  const float* vn_b1     = (const float*)d_in[19];
  const float* vn_bn1_g  = (const float*)d_in[20];
  const float* vn_bn1_b  = (const float*)d_in[21];
  const float* vn_W2     = (const float*)d_in[22];
  const float* vn_b2     = (const float*)d_in[23];
  const float* vn_bn2_g  = (const float*)d_in[24];
  const float* vn_bn2_b  = (const float*)d_in[25];

  char* wsb = (char*)d_ws;
  size_t off = 0;
  auto take = [&](size_t bytes) -> void* {
    void* p = wsb + off;
    off += (bytes + 255) & ~(size_t)255;
    return p;
  };
  int*    counts  = (int*)take((size_t)2 * N_NODES * 4);
  int*    cursor  = counts + N_NODES;
  float*  stats   = (float*)take((size_t)NLAYER * 12288 * 4);
  size_t  memset_bytes = (size_t)2 * N_NODES * 4 + (size_t)NLAYER * 12288 * 4;
  __bf16* h_hi    = (__bf16*)take((size_t)N_NODES * DIM * 2);
  __bf16* h_lo    = (__bf16*)take((size_t)N_NODES * DIM * 2);
  float*  y2      = (float*)take((size_t)N_NODES * DIM * 4);
  __bf16* y1h     = (__bf16*)take((size_t)N_NODES * TWO_D * 2);
  __bf16* y1l     = (__bf16*)take((size_t)N_NODES * TWO_D * 2);
  __bf16* z_hi    = (__bf16*)take((size_t)N_NODES * DIM * 2);
  __bf16* z_lo    = (__bf16*)take((size_t)N_NODES * DIM * 2);
  int*    csr_src = (int*)take((size_t)N_EDGES * 4);
  __bf16* ea_csr  = (__bf16*)take((size_t)N_EDGES * 8 * 2);
  int*    perm    = (int*)take((size_t)N_EDGES * 4);
  int*    offsets = (int*)take((size_t)(N_NODES + 1) * 4);
  int*    slocal  = (int*)take((size_t)(N_NODES + 1024) * 4);
  int*    sbsum   = (int*)take(64 * 4);
  int*    scarry  = sbsum + 32;
  int*    gs      = (int*)take((size_t)(NGRAPH + 1) * 4);
  float*  pooled  = (float*)take((size_t)NGRAPH * DIM * 4);
  float*  tv      = (float*)take((size_t)NGRAPH * TWO_D * 4);
  float*  vnr     = (float*)take((size_t)NGRAPH * DIM * 4);
  float*  vn0     = (float*)take((size_t)NGRAPH * DIM * 4);
  __bf16* encT_hi = (__bf16*)take((size_t)DIM * DIM * 2);
  __bf16* encT_lo = (__bf16*)take((size_t)DIM * DIM * 2);
  __bf16* W1T_hi  = (__bf16*)take((size_t)NLAYER * DIM * TWO_D * 2);
  __bf16* W1T_lo  = (__bf16*)take((size_t)NLAYER * DIM * TWO_D * 2);
  __bf16* W2T_hi  = (__bf16*)take((size_t)NLAYER * TWO_D * DIM * 2);
  __bf16* W2T_lo  = (__bf16*)take((size_t)NLAYER * TWO_D * DIM * 2);
  if (off > ws_size) return;

  const int* srcArr = edge_index;
  const int* dstArr = edge_index + N_EDGES;

  hipMemsetAsync(counts, 0, memset_bytes, stream);

  k_hist<<<N_EDGES / 256, 256, 0, stream>>>(dstArr, counts);
  k_scanA<<<20, 1024, 0, stream>>>(counts, slocal, sbsum);
  k_scanB<<<1, 256, 0, stream>>>(sbsum, scarry, offsets, batch, gs);
  k_scanC<<<20, 1024, 0, stream>>>(slocal, scarry, offsets);
  k_fillA<<<N_EDGES / 256, 256, 0, stream>>>(dstArr, offsets, cursor, perm);
  k_fillB<<<N_EDGES / 256, 256, 0, stream>>>(perm, srcArr, edge_attr, csr_src, ea_csr);
  k_convAll<<<336, 1024, 0, stream>>>(enc_W, mlp_W1, mlp_W2,
      encT_hi, encT_lo, W1T_hi, W1T_lo, W2T_hi, W2T_lo);
  k_vninit<<<(NGRAPH * DIM) / 256, 256, 0, stream>>>(vn_emb, vn0);
  k_enc<<<N_NODES / 32, 128, 0, stream>>>(x, encT_hi, encT_lo, enc_b, vn_emb, h_hi, h_lo);

  for (int l = 0; l < NLAYER; ++l) {
    float* s1  = stats + (size_t)l * 12288;
    float* q1  = s1 + 2048;
    float* s2  = s1 + 4096;
    float* q2  = s1 + 5120;
    float* sv1 = s1 + 6144;
    float* qv1 = s1 + 8192;
    float* sv2 = s1 + 10240;
    float* qv2 = s1 + 11264;
    if (l < NLAYER - 1) {
      if (l == 0)
        k_pool<<<NGRAPH, 1024, 0, stream>>>(h_hi, gs, vn0, vn0, nullptr, nullptr,
            nullptr, nullptr, 0, pooled);
      else {
        float* psv2 = stats + (size_t)(l - 1) * 12288 + 10240;
        float* pqv2 = stats + (size_t)(l - 1) * 12288 + 11264;
        k_pool<<<NGRAPH, 1024, 0, stream>>>(h_hi, gs, vn0, vnr, psv2, pqv2,
            vn_bn2_g + (size_t)(l - 1) * DIM, vn_bn2_b + (size_t)(l - 1) * DIM, 1, pooled);
      }
    }
    k_agg<<<N_NODES / 4, 256, 0, stream>>>(h_hi, h_lo, offsets, csr_src, ea_csr,
        edge_W + (size_t)l * EDIM * DIM, edge_b + (size_t)l * DIM, eps, l, z_hi, z_lo);
    k_gemm1<<<N_NODES / 32, 256, 0, stream>>>(z_hi, z_lo,
        W1T_hi + (size_t)l * DIM * TWO_D, W1T_lo + (size_t)l * DIM * TWO_D,
        mlp_b1 + (size_t)l * TWO_D, y1h, y1l, s1, q1);
    k_gemm2<<<N_NODES / 32, 256, 0, stream>>>(y1h, y1l,
        W2T_hi + (size_t)l * TWO_D * DIM, W2T_lo + (size_t)l * TWO_D * DIM,
        mlp_b2 + (size_t)l * DIM, s1, q1,
        mlp_bn1_g + (size_t)l * TWO_D, mlp_bn1_b + (size_t)l * TWO_D,
        y2, s2, q2);
    if (l < NLAYER - 1) {
      k_vgemm1<<<NGRAPH, 256, 0, stream>>>(pooled, vn_W1 + (size_t)l * DIM * TWO_D,
          vn_b1 + (size_t)l * TWO_D, tv, sv1, qv1);
      k_vgemm2<<<NGRAPH, 256, 0, stream>>>(tv, sv1, qv1,
          vn_bn1_g + (size_t)l * TWO_D, vn_bn1_b + (size_t)l * TWO_D,
          vn_W2 + (size_t)l * TWO_D * DIM, vn_b2 + (size_t)l * DIM,
          vnr, sv2, qv2);
      k_bn2hin<<<(N_NODES * 32) / 256, 256, 0, stream>>>(y2, s2, q2,
          bn_g + (size_t)l * DIM, bn_b + (size_t)l * DIM,
          vnr, sv2, qv2, vn_bn2_g + (size_t)l * DIM, vn_bn2_b + (size_t)l * DIM,
          batch, h_hi, h_lo);
    } else {
      k_out<<<(N_NODES * 32) / 256, 256, 0, stream>>>(y2, s2, q2,
          bn_g + (size_t)l * DIM, bn_b + (size_t)l * DIM, (float*)d_out);
    }
  }
}

// Round 15
// 689.859 us; speedup vs baseline: 1.4556x; 1.1185x over previous
//
#include <hip/hip_runtime.h>

#define N_NODES 20000
#define N_EDGES 640000
#define DIM 128
#define NGRAPH 128
#define NLAYER 5
#define EDIM 7
#define TWO_D 256

typedef __bf16 bf16x8 __attribute__((ext_vector_type(8)));
typedef __bf16 bf16x4 __attribute__((ext_vector_type(4)));
typedef __bf16 bf16x2 __attribute__((ext_vector_type(2)));
typedef float  f32x4  __attribute__((ext_vector_type(4)));

__device__ __forceinline__ f32x4 mfma16(bf16x8 a, bf16x8 b, f32x4 c) {
  return __builtin_amdgcn_mfma_f32_16x16x32_bf16(a, b, c, 0, 0, 0);
}

// ---------------- CSR build ----------------
__global__ void k_hist(const int* __restrict__ dst, int* __restrict__ counts) {
  int e = blockIdx.x * blockDim.x + threadIdx.x;
  if (e < N_EDGES) atomicAdd(&counts[dst[e]], 1);
}

__global__ __launch_bounds__(1024) void k_scanA(const int* __restrict__ counts,
    int* __restrict__ local, int* __restrict__ bsum) {
  __shared__ int sd[1024];
  int b = blockIdx.x, tid = threadIdx.x;
  int i = b * 1024 + tid;
  int v = (i < N_NODES) ? counts[i] : 0;
  sd[tid] = v;
  __syncthreads();
  for (int ofs = 1; ofs < 1024; ofs <<= 1) {
    int t = (tid >= ofs) ? sd[tid - ofs] : 0;
    __syncthreads();
    sd[tid] += t;
    __syncthreads();
  }
  if (i <= N_NODES) local[i] = sd[tid] - v;  // exclusive
  if (tid == 1023) bsum[b] = sd[1023];
}

// carry pass + graph-segment starts
__global__ void k_scanB(int* __restrict__ bsum, int* __restrict__ carry,
                        int* __restrict__ offsets, const int* __restrict__ batch,
                        int* __restrict__ gs) {
  int tid = threadIdx.x;
  if (tid == 0) {
    int run = 0;
    for (int b = 0; b < 20; ++b) { carry[b] = run; run += bsum[b]; }
    offsets[N_NODES] = run;
  }
  if (tid <= NGRAPH) {
    if (tid == NGRAPH) gs[NGRAPH] = N_NODES;
    else {
      int lo = 0, hi = N_NODES;
      while (lo < hi) { int mid = (lo + hi) >> 1; if (batch[mid] < tid) lo = mid + 1; else hi = mid; }
      gs[tid] = lo;
    }
  }
}

__global__ __launch_bounds__(1024) void k_scanC(const int* __restrict__ local,
    const int* __restrict__ carry, int* __restrict__ offsets) {
  int i = blockIdx.x * 1024 + threadIdx.x;
  if (i < N_NODES) offsets[i] = local[i] + carry[i >> 10];
}

// fill pass A: only the unavoidable random write (4B perm scatter)
__global__ void k_fillA(const int* __restrict__ dstArr, const int* __restrict__ offsets,
                        int* __restrict__ cursor, int* __restrict__ perm) {
  int e = blockIdx.x * blockDim.x + threadIdx.x;
  if (e >= N_EDGES) return;
  int d = dstArr[e];
  int p = offsets[d] + atomicAdd(&cursor[d], 1);
  perm[p] = e;
}

// fill pass B: coalesced over CSR slots; random READS, sequential writes
__global__ void k_fillB(const int* __restrict__ perm, const int* __restrict__ srcArr,
                        const float* __restrict__ edge_attr,
                        int* __restrict__ csr_src, __bf16* __restrict__ ea_csr) {
  int i = blockIdx.x * blockDim.x + threadIdx.x;
  if (i >= N_EDGES) return;
  int e = perm[i];
  csr_src[i] = srcArr[e];
  const float* ea = edge_attr + (size_t)e * EDIM;
  bf16x8 v;
#pragma unroll
  for (int k = 0; k < EDIM; ++k) v[k] = (__bf16)ea[k];
  v[7] = (__bf16)0.f;
  *(bf16x8*)(ea_csr + (size_t)i * 8) = v;
}

// ---------------- all weight transposes (hi/lo split) in one launch ----------------
__global__ void k_convAll(const float* __restrict__ encW, const float* __restrict__ W1,
    const float* __restrict__ W2,
    __bf16* __restrict__ encT_hi, __bf16* __restrict__ encT_lo,
    __bf16* __restrict__ W1T_hi, __bf16* __restrict__ W1T_lo,
    __bf16* __restrict__ W2T_hi, __bf16* __restrict__ W2T_lo) {
  const int t1 = DIM * DIM;
  const int t2 = NLAYER * DIM * TWO_D;
  const int total = t1 + t2 + t2;
  for (int i = blockIdx.x * blockDim.x + threadIdx.x; i < total;
       i += gridDim.x * blockDim.x) {
    const float* src; __bf16 *dh, *dl; int K, C, idx;
    if (i < t1)            { src = encW; dh = encT_hi; dl = encT_lo; K = DIM;   C = DIM;   idx = i; }
    else if (i < t1 + t2)  { src = W1;   dh = W1T_hi;  dl = W1T_lo;  K = DIM;   C = TWO_D; idx = i - t1; }
    else                   { src = W2;   dh = W2T_hi;  dl = W2T_lo;  K = TWO_D; C = DIM;   idx = i - t1 - t2; }
    int l = idx / (K * C);
    int rem = idx - l * K * C;
    int k = rem / C;
    int c = rem - k * C;
    float v = src[idx];
    __bf16 hi = (__bf16)v;
    __bf16 lo = (__bf16)(v - (float)hi);
    size_t o = (size_t)l * K * C + (size_t)c * K + k;
    dh[o] = hi;
    dl[o] = lo;
  }
}

__global__ void k_vninit(const float* __restrict__ vn_emb, float* __restrict__ vn) {
  int i = blockIdx.x * blockDim.x + threadIdx.x;
  if (i < NGRAPH * DIM) vn[i] = vn_emb[i & (DIM - 1)];
}

// ---------------- encoder GEMM: h = x @ encW + enc_b + vn_emb (hi/lo out) ----------------
__global__ __launch_bounds__(128) void k_enc(const float* __restrict__ x,
    const __bf16* __restrict__ encT_hi, const __bf16* __restrict__ encT_lo,
    const float* __restrict__ enc_b, const float* __restrict__ vn_emb,
    __bf16* __restrict__ h_hi, __bf16* __restrict__ h_lo) {
  int lane = threadIdx.x & 63, wid = threadIdx.x >> 6;
  int rbase = blockIdx.x * 32 + wid * 16;
  int r = rbase + (lane & 15);
  int ko = (lane >> 4) * 8;
  const float* xr = x + (size_t)r * DIM;
  bf16x8 a_hi[4], a_lo[4];
#pragma unroll
  for (int ks = 0; ks < 4; ++ks) {
    f32x4 v0 = *(const f32x4*)(xr + ks * 32 + ko);
    f32x4 v1 = *(const f32x4*)(xr + ks * 32 + ko + 4);
    bf16x8 th, tl;
#pragma unroll
    for (int j = 0; j < 4; ++j) {
      th[j] = (__bf16)v0[j];     tl[j] = (__bf16)(v0[j] - (float)th[j]);
      th[4+j] = (__bf16)v1[j];   tl[4+j] = (__bf16)(v1[j] - (float)th[4+j]);
    }
    a_hi[ks] = th; a_lo[ks] = tl;
  }
  const f32x4 fz = {0.f, 0.f, 0.f, 0.f};
  f32x4 acc[8];
#pragma unroll
  for (int nf = 0; nf < 8; ++nf) acc[nf] = fz;
#pragma unroll
  for (int nf = 0; nf < 8; ++nf) {
    size_t wrow = (size_t)(nf * 16 + (lane & 15)) * DIM + ko;
    const __bf16* bh = encT_hi + wrow;
    const __bf16* bl = encT_lo + wrow;
#pragma unroll
    for (int ks = 0; ks < 4; ++ks) {
      bf16x8 wh = *(const bf16x8*)(bh + ks * 32);
      bf16x8 wl = *(const bf16x8*)(bl + ks * 32);
      acc[nf] = mfma16(a_hi[ks], wh, acc[nf]);
      acc[nf] = mfma16(a_lo[ks], wh, acc[nf]);
      acc[nf] = mfma16(a_hi[ks], wl, acc[nf]);
    }
  }
  int c0 = lane & 15;
  int rr = rbase + (lane >> 4) * 4;
#pragma unroll
  for (int nf = 0; nf < 8; ++nf) {
    int c = nf * 16 + c0;
    float bias = enc_b[c] + vn_emb[c];
#pragma unroll
    for (int j = 0; j < 4; ++j) {
      float v = acc[nf][j] + bias;
      __bf16 hi = (__bf16)v;
      h_hi[(size_t)(rr + j) * DIM + c] = hi;
      h_lo[(size_t)(rr + j) * DIM + c] = (__bf16)(v - (float)hi);
    }
  }
}

// ---------------- per-graph pool: pooled = segsum(h_hi) + vn ----------------
__global__ __launch_bounds__(1024) void k_pool(const __bf16* __restrict__ h_hi,
    const int* __restrict__ gs, const float* __restrict__ vnbuf,
    const float* __restrict__ vnr, const float* __restrict__ sv2,
    const float* __restrict__ qv2, const float* __restrict__ bn2g,
    const float* __restrict__ bn2b, int use_stats,
    float* __restrict__ pooled) {
  __shared__ float red[8][DIM];
  __shared__ float vns[DIM];
  int tid = threadIdx.x;
  int g = blockIdx.x;
  if (tid < DIM) {
    if (use_stats) {
      float s = 0.f, q = 0.f;
#pragma unroll
      for (int rep = 0; rep < 8; ++rep) { s += sv2[rep * DIM + tid]; q += qv2[rep * DIM + tid]; }
      float m = s * (1.f / NGRAPH);
      float var = q * (1.f / NGRAPH) - m * m;
      float a = bn2g[tid] / sqrtf(var + 1e-5f);
      vns[tid] = fmaxf(vnr[g * DIM + tid] * a + (bn2b[tid] - m * a), 0.f);
    } else {
      vns[tid] = vnbuf[g * DIM + tid];
    }
  }
  __syncthreads();
  int d = tid & 127, slot = tid >> 7;
  int lo = gs[g], hi = gs[g + 1];
  float acc = 0.f;
  for (int n = lo + slot; n < hi; n += 8)
    acc += (float)h_hi[(size_t)n * DIM + d];
  red[slot][d] = acc;
  __syncthreads();
  if (slot == 0) {
    float t = vns[d];
#pragma unroll
    for (int s2 = 0; s2 < 8; ++s2) t += red[s2][d];
    pooled[g * DIM + d] = t;
  }
}

// ---------------- GIN aggregation -> z (hi/lo split) ----------------
// Wave-per-node, contiguous edge stream, unroll 4 -> 4 gathers in flight.
// (Proven best form: rounds 11/13/14 A/B'd 2-node-per-wave and SW-pipeline
// variants; both regressed. Keep this one.)
__global__ __launch_bounds__(256) void k_agg(const __bf16* __restrict__ h_hi,
    const __bf16* __restrict__ h_lo, const int* __restrict__ offsets,
    const int* __restrict__ csr_src, const __bf16* __restrict__ ea_csr,
    const float* __restrict__ eW, const float* __restrict__ eB,
    const float* __restrict__ eps, int l,
    __bf16* __restrict__ z_hi, __bf16* __restrict__ z_lo) {
  int tid = threadIdx.x;
  int lane = tid & 63, w = tid >> 6;
  int l2 = lane * 2;
  int n = blockIdx.x * 4 + w;
  float w0[EDIM], w1[EDIM];
#pragma unroll
  for (int k = 0; k < EDIM; ++k) {
    float2 wv = *(const float2*)(eW + k * DIM + l2);
    w0[k] = wv.x; w1[k] = wv.y;
  }
  float2 ebv = *(const float2*)(eB + l2);
  int off = offsets[n], end = offsets[n + 1];
  float acc0 = 0.f, acc1 = 0.f;

  auto edge = [&](int iu) {
    int s = csr_src[iu];
    const unsigned* eu = (const unsigned*)(ea_csr + (size_t)iu * 8);
    unsigned u0 = eu[0], u1 = eu[1], u2 = eu[2], u3 = eu[3];
    unsigned hv = *(const unsigned*)(h_hi + (size_t)s * DIM + l2);
    float e0 = __builtin_bit_cast(float, u0 << 16);
    float e1 = __builtin_bit_cast(float, u0 & 0xffff0000u);
    float e2 = __builtin_bit_cast(float, u1 << 16);
    float e3 = __builtin_bit_cast(float, u1 & 0xffff0000u);
    float e4 = __builtin_bit_cast(float, u2 << 16);
    float e5 = __builtin_bit_cast(float, u2 & 0xffff0000u);
    float e6 = __builtin_bit_cast(float, u3 << 16);
    float m0 = __builtin_bit_cast(float, hv << 16) + ebv.x;
    float m1 = __builtin_bit_cast(float, hv & 0xffff0000u) + ebv.y;
    m0 = fmaf(e0, w0[0], m0); m1 = fmaf(e0, w1[0], m1);
    m0 = fmaf(e1, w0[1], m0); m1 = fmaf(e1, w1[1], m1);
    m0 = fmaf(e2, w0[2], m0); m1 = fmaf(e2, w1[2], m1);
    m0 = fmaf(e3, w0[3], m0); m1 = fmaf(e3, w1[3], m1);
    m0 = fmaf(e4, w0[4], m0); m1 = fmaf(e4, w1[4], m1);
    m0 = fmaf(e5, w0[5], m0); m1 = fmaf(e5, w1[5], m1);
    m0 = fmaf(e6, w0[6], m0); m1 = fmaf(e6, w1[6], m1);
    acc0 += fmaxf(m0, 0.f);
    acc1 += fmaxf(m1, 0.f);
  };

  int i = off;
  for (; i + 3 < end; i += 4) {
    int iu = __builtin_amdgcn_readfirstlane(i);
    edge(iu);
    edge(iu + 1);
    edge(iu + 2);
    edge(iu + 3);
  }
  for (; i < end; ++i) {
    edge(__builtin_amdgcn_readfirstlane(i));
  }
  float epsv = 1.f + eps[l];
  unsigned hvh = *(const unsigned*)(h_hi + (size_t)n * DIM + l2);
  unsigned hvl = *(const unsigned*)(h_lo + (size_t)n * DIM + l2);
  float s0 = __builtin_bit_cast(float, hvh << 16) + __builtin_bit_cast(float, hvl << 16);
  float s1 = __builtin_bit_cast(float, hvh & 0xffff0000u) + __builtin_bit_cast(float, hvl & 0xffff0000u);
  float v0 = epsv * s0 + acc0;
  float v1 = epsv * s1 + acc1;
  __bf16 hi0 = (__bf16)v0, hi1 = (__bf16)v1;
  bf16x2 zh; zh[0] = hi0; zh[1] = hi1;
  bf16x2 zl; zl[0] = (__bf16)(v0 - (float)hi0); zl[1] = (__bf16)(v1 - (float)hi1);
  *(bf16x2*)(z_hi + (size_t)n * DIM + l2) = zh;
  *(bf16x2*)(z_lo + (size_t)n * DIM + l2) = zl;
}

// ---------------- GEMM1: y1 = z @ W1 + b1 (+ BN1 stats), y1 bf16 ----------------
// 16-row blocks, 4 waves split columns (grid 1250 -> 5000 waves).
__global__ __launch_bounds__(256) void k_gemm1(const __bf16* __restrict__ z_hi,
    const __bf16* __restrict__ z_lo,
    const __bf16* __restrict__ W1T_hi, const __bf16* __restrict__ W1T_lo,
    const float* __restrict__ b1,
    __bf16* __restrict__ y1h,
    float* __restrict__ s1, float* __restrict__ q1) {
  int tid = threadIdx.x;
  int lane = tid & 63, wid = tid >> 6;   // wid = column quarter
  int rbase = blockIdx.x * 16;
  int r = rbase + (lane & 15);
  int ko = (lane >> 4) * 8;
  bf16x8 a_hi[4], a_lo[4];
#pragma unroll
  for (int ks = 0; ks < 4; ++ks) {
    a_hi[ks] = *(const bf16x8*)(z_hi + (size_t)r * DIM + ks * 32 + ko);
    a_lo[ks] = *(const bf16x8*)(z_lo + (size_t)r * DIM + ks * 32 + ko);
  }
  const f32x4 fz = {0.f, 0.f, 0.f, 0.f};
  f32x4 acc[4];
#pragma unroll
  for (int nf4 = 0; nf4 < 4; ++nf4) acc[nf4] = fz;
#pragma unroll
  for (int nf4 = 0; nf4 < 4; ++nf4) {
    int nf = wid * 4 + nf4;
    size_t wrow = (size_t)(nf * 16 + (lane & 15)) * DIM + ko;
    const __bf16* bh = W1T_hi + wrow;
    const __bf16* bl = W1T_lo + wrow;
#pragma unroll
    for (int ks = 0; ks < 4; ++ks) {
      bf16x8 wh = *(const bf16x8*)(bh + ks * 32);
      bf16x8 wl = *(const bf16x8*)(bl + ks * 32);
      acc[nf4] = mfma16(a_hi[ks], wh, acc[nf4]);
      acc[nf4] = mfma16(a_lo[ks], wh, acc[nf4]);
      acc[nf4] = mfma16(a_hi[ks], wl, acc[nf4]);
    }
  }
  int c0 = lane & 15;
  int rr = rbase + (lane >> 4) * 4;
  int rep = blockIdx.x & 7;
#pragma unroll
  for (int nf4 = 0; nf4 < 4; ++nf4) {
    int c = (wid * 4 + nf4) * 16 + c0;
    float bias = b1[c];
    float s = 0.f, q = 0.f;
#pragma unroll
    for (int j = 0; j < 4; ++j) {
      float v = acc[nf4][j] + bias;
      y1h[(size_t)(rr + j) * TWO_D + c] = (__bf16)v;
      s += v; q += v * v;
    }
    s += __shfl_xor(s, 16); s += __shfl_xor(s, 32);
    q += __shfl_xor(q, 16); q += __shfl_xor(q, 32);
    if (lane < 16) {
      atomicAdd(&s1[rep * TWO_D + c], s);
      atomicAdd(&q1[rep * TWO_D + c], q);
    }
  }
}

// ---------------- GEMM2: prologue computes BN1 scale/shift from stats ----------------
// 16-row blocks, 4 waves split columns (grid 1250).
__global__ __launch_bounds__(256) void k_gemm2(const __bf16* __restrict__ y1h,
    const __bf16* __restrict__ W2T_hi, const __bf16* __restrict__ W2T_lo,
    const float* __restrict__ b2,
    const float* __restrict__ s1, const float* __restrict__ q1,
    const float* __restrict__ bn1g, const float* __restrict__ bn1b,
    float* __restrict__ y2, float* __restrict__ s2, float* __restrict__ q2) {
  __shared__ float sc1s[TWO_D], sh1s[TWO_D];
  int tid = threadIdx.x;
  {
    int c = tid;
    float s = 0.f, q = 0.f;
#pragma unroll
    for (int rep = 0; rep < 8; ++rep) { s += s1[rep * TWO_D + c]; q += q1[rep * TWO_D + c]; }
    float m = s * (1.f / N_NODES);
    float var = q * (1.f / N_NODES) - m * m;
    float a = bn1g[c] / sqrtf(var + 1e-5f);
    sc1s[c] = a; sh1s[c] = bn1b[c] - m * a;
  }
  __syncthreads();
  int lane = tid & 63, wid = tid >> 6;  // wid = column quarter
  int rbase = blockIdx.x * 16;
  int r = rbase + (lane & 15);
  int ko = (lane >> 4) * 8;
  bf16x8 a_hi[8], a_lo[8];
#pragma unroll
  for (int ks = 0; ks < 8; ++ks) {
    int kb = ks * 32 + ko;
    bf16x8 rh = *(const bf16x8*)(y1h + (size_t)r * TWO_D + kb);
    f32x4 sc0 = *(const f32x4*)(&sc1s[kb]);
    f32x4 sc1 = *(const f32x4*)(&sc1s[kb + 4]);
    f32x4 sh0 = *(const f32x4*)(&sh1s[kb]);
    f32x4 sh1 = *(const f32x4*)(&sh1s[kb + 4]);
    bf16x8 th, tl;
#pragma unroll
    for (int j = 0; j < 4; ++j) {
      float v0 = fmaxf((float)rh[j] * sc0[j] + sh0[j], 0.f);
      float v1 = fmaxf((float)rh[4 + j] * sc1[j] + sh1[j], 0.f);
      th[j] = (__bf16)v0;     tl[j] = (__bf16)(v0 - (float)th[j]);
      th[4+j] = (__bf16)v1;   tl[4+j] = (__bf16)(v1 - (float)th[4+j]);
    }
    a_hi[ks] = th; a_lo[ks] = tl;
  }
  const f32x4 fz = {0.f, 0.f, 0.f, 0.f};
  f32x4 acc[2];
#pragma unroll
  for (int nf2 = 0; nf2 < 2; ++nf2) acc[nf2] = fz;
#pragma unroll
  for (int nf2 = 0; nf2 < 2; ++nf2) {
    int nf = wid * 2 + nf2;
    size_t wrow = (size_t)(nf * 16 + (lane & 15)) * TWO_D + ko;
    const __bf16* bh = W2T_hi + wrow;
    const __bf16* bl = W2T_lo + wrow;
#pragma unroll
    for (int ks = 0; ks < 8; ++ks) {
      bf16x8 wh = *(const bf16x8*)(bh + ks * 32);
      bf16x8 wl = *(const bf16x8*)(bl + ks * 32);
      acc[nf2] = mfma16(a_hi[ks], wh, acc[nf2]);
      acc[nf2] = mfma16(a_lo[ks], wh, acc[nf2]);
      acc[nf2] = mfma16(a_hi[ks], wl, acc[nf2]);
    }
  }
  int c0 = lane & 15;
  int rr = rbase + (lane >> 4) * 4;
  int rep = blockIdx.x & 7;
#pragma unroll
  for (int nf2 = 0; nf2 < 2; ++nf2) {
    int c = (wid * 2 + nf2) * 16 + c0;
    float bias = b2[c];
    float s = 0.f, q = 0.f;
#pragma unroll
    for (int j = 0; j < 4; ++j) {
      float v = acc[nf2][j] + bias;
      y2[(size_t)(rr + j) * DIM + c] = v;
      s += v; q += v * v;
    }
    s += __shfl_xor(s, 16); s += __shfl_xor(s, 32);
    q += __shfl_xor(q, 16); q += __shfl_xor(q, 32);
    if (lane < 16) {
      atomicAdd(&s2[rep * DIM + c], s);
      atomicAdd(&q2[rep * DIM + c], q);
    }
  }
}

// ---------------- fused virtual-node GEMM1 (+ col stats) ----------------
__global__ __launch_bounds__(256) void k_vgemm1(const float* __restrict__ pooled,
    const float* __restrict__ W1, const float* __restrict__ b1,
    float* __restrict__ tv, float* __restrict__ sv1, float* __restrict__ qv1) {
  __shared__ float row[DIM];
  int g = blockIdx.x, tid = threadIdx.x;
  if (tid < DIM) row[tid] = pooled[g * DIM + tid];
  __syncthreads();
  int c = tid;
  float acc = b1[c];
  for (int k = 0; k < DIM; ++k) acc = fmaf(row[k], W1[k * TWO_D + c], acc);
  tv[g * TWO_D + c] = acc;
  int rep = g & 7;
  atomicAdd(&sv1[rep * TWO_D + c], acc);
  atomicAdd(&qv1[rep * TWO_D + c], acc * acc);
}

// ---------------- fused virtual-node BN1+relu+GEMM2 (+ col stats) ----------------
__global__ __launch_bounds__(256) void k_vgemm2(const float* __restrict__ tv,
    const float* __restrict__ sv1, const float* __restrict__ qv1,
    const float* __restrict__ bn1g, const float* __restrict__ bn1b,
    const float* __restrict__ W2, const float* __restrict__ b2,
    float* __restrict__ vnr, float* __restrict__ sv2, float* __restrict__ qv2) {
  __shared__ float trow[TWO_D];
  int g = blockIdx.x, tid = threadIdx.x;
  {
    float s = 0.f, q = 0.f;
#pragma unroll
    for (int rep = 0; rep < 8; ++rep) { s += sv1[rep * TWO_D + tid]; q += qv1[rep * TWO_D + tid]; }
    float m = s * (1.f / NGRAPH);
    float var = q * (1.f / NGRAPH) - m * m;
    float a = bn1g[tid] / sqrtf(var + 1e-5f);
    trow[tid] = fmaxf(tv[g * TWO_D + tid] * a + (bn1b[tid] - m * a), 0.f);
  }
  __syncthreads();
  if (tid < DIM) {
    float acc = b2[tid];
    for (int k = 0; k < TWO_D; ++k) acc = fmaf(trow[k], W2[k * DIM + tid], acc);
    vnr[g * DIM + tid] = acc;
    int rep = g & 7;
    atomicAdd(&sv2[rep * DIM + tid], acc);
    atomicAdd(&qv2[rep * DIM + tid], acc * acc);
  }
}

// ---------------- fused BN2 finalize + relu + vn(BN2+relu) gather -> h_hi/h_lo ----------------
__global__ __launch_bounds__(256) void k_bn2hin(const float* __restrict__ y2,
    const float* __restrict__ s2, const float* __restrict__ q2,
    const float* __restrict__ bng, const float* __restrict__ bnb,
    const float* __restrict__ vnr, const float* __restrict__ sv2,
    const float* __restrict__ qv2, const float* __restrict__ vbn2g,
    const float* __restrict__ vbn2b, const int* __restrict__ batch,
    __bf16* __restrict__ h_hi, __bf16* __restrict__ h_lo) {
  __shared__ float sc2s[DIM], sh2s[DIM], scvn[DIM], shvn[DIM];
  int tid = threadIdx.x;
  if (tid < DIM) {
    float s = 0.f, q = 0.f;
#pragma unroll
    for (int rep = 0; rep < 8; ++rep) { s += s2[rep * DIM + tid]; q += q2[rep * DIM + tid]; }
    float m = s * (1.f / N_NODES);
    float var = q * (1.f / N_NODES) - m * m;
    float a = bng[tid] / sqrtf(var + 1e-5f);
    sc2s[tid] = a; sh2s[tid] = bnb[tid] - m * a;
    float sv = 0.f, qv = 0.f;
#pragma unroll
    for (int rep = 0; rep < 8; ++rep) { sv += sv2[rep * DIM + tid]; qv += qv2[rep * DIM + tid]; }
    float mv = sv * (1.f / NGRAPH);
    float varv = qv * (1.f / NGRAPH) - mv * mv;
    float av = vbn2g[tid] / sqrtf(varv + 1e-5f);
    scvn[tid] = av; shvn[tid] = vbn2b[tid] - mv * av;
  }
  __syncthreads();
  int idx = blockIdx.x * 256 + tid;
  if (idx >= N_NODES * (DIM / 4)) return;
  int c4 = idx & 31;
  int row = idx >> 5;
  f32x4 y = ((const f32x4*)y2)[idx];
  f32x4 scv = ((const f32x4*)sc2s)[c4];
  f32x4 shv = ((const f32x4*)sh2s)[c4];
  f32x4 vsc = ((const f32x4*)scvn)[c4];
  f32x4 vsh = ((const f32x4*)shvn)[c4];
  int b = batch[row];
  f32x4 vr = ((const f32x4*)vnr)[b * 32 + c4];
  bf16x4 oh, ol;
#pragma unroll
  for (int j = 0; j < 4; ++j) {
    float vnv = fmaxf(vr[j] * vsc[j] + vsh[j], 0.f);
    float o = fmaxf(y[j] * scv[j] + shv[j], 0.f) + vnv;
    __bf16 hi = (__bf16)o;
    oh[j] = hi;
    ol[j] = (__bf16)(o - (float)hi);
  }
  ((bf16x4*)h_hi)[idx] = oh;
  ((bf16x4*)h_lo)[idx] = ol;
}

__global__ __launch_bounds__(256) void k_out(const float* __restrict__ y2,
    const float* __restrict__ s2, const float* __restrict__ q2,
    const float* __restrict__ bng, const float* __restrict__ bnb,
    float* __restrict__ out) {
  __shared__ float sc2s[DIM], sh2s[DIM];
  int tid = threadIdx.x;
  if (tid < DIM) {
    float s = 0.f, q = 0.f;
#pragma unroll
    for (int rep = 0; rep < 8; ++rep) { s += s2[rep * DIM + tid]; q += q2[rep * DIM + tid]; }
    float m = s * (1.f / N_NODES);
    float var = q * (1.f / N_NODES) - m * m;
    float a = bng[tid] / sqrtf(var + 1e-5f);
    sc2s[tid] = a; sh2s[tid] = bnb[tid] - m * a;
  }
  __syncthreads();
  int idx = blockIdx.x * 256 + tid;
  if (idx >= N_NODES * (DIM / 4)) return;
  int c4 = idx & 31;
  f32x4 y = ((const f32x4*)y2)[idx];
  f32x4 scv = ((const f32x4*)sc2s)[c4];
  f32x4 shv = ((const f32x4*)sh2s)[c4];
  f32x4 o;
#pragma unroll
  for (int j = 0; j < 4; ++j) o[j] = y[j] * scv[j] + shv[j];
  ((f32x4*)out)[idx] = o;
}

// ---------------- host ----------------
extern "C" void kernel_launch(void* const* d_in, const int* in_sizes, int n_in,
                              void* d_out, int out_size, void* d_ws, size_t ws_size,
                              hipStream_t stream) {
  const float* x         = (const float*)d_in[0];
  const float* edge_attr = (const float*)d_in[1];
  const int*   edge_index= (const int*)d_in[2];
  const int*   batch     = (const int*)d_in[3];
  const float* enc_W     = (const float*)d_in[4];
  const float* enc_b     = (const float*)d_in[5];
  const float* vn_emb    = (const float*)d_in[6];
  const float* eps       = (const float*)d_in[7];
  const float* edge_W    = (const float*)d_in[8];
  const float* edge_b    = (const float*)d_in[9];
  const float* mlp_W1    = (const float*)d_in[10];
  const float* mlp_b1    = (const float*)d_in[11];
  const float* mlp_bn1_g = (const float*)d_in[12];
  const float* mlp_bn1_b = (const float*)d_in[13];
  const float* mlp_W2    = (const float*)d_in[14];
  const float* mlp_b2    = (const float*)d_in[15];
  const float* bn_g      = (const float*)d_in[16];
  const float* bn_b      = (const float*)d_in[17];
  const float* vn_W1     = (const float*)d_in[18];
  const float* vn_b1     = (const float*)d_in[19];
  const float* vn_bn1_g  = (const float*)d_in[20];
  const float* vn_bn1_b  = (const float*)d_in[21];
  const float* vn_W2     = (const float*)d_in[22];
  const float* vn_b2     = (const float*)d_in[23];
  const float* vn_bn2_g  = (const float*)d_in[24];
  const float* vn_bn2_b  = (const float*)d_in[25];

  char* wsb = (char*)d_ws;
  size_t off = 0;
  auto take = [&](size_t bytes) -> void* {
    void* p = wsb + off;
    off += (bytes + 255) & ~(size_t)255;
    return p;
  };
  int*    counts  = (int*)take((size_t)2 * N_NODES * 4);
  int*    cursor  = counts + N_NODES;
  float*  stats   = (float*)take((size_t)NLAYER * 12288 * 4);
  size_t  memset_bytes = (size_t)2 * N_NODES * 4 + (size_t)NLAYER * 12288 * 4;
  __bf16* h_hi    = (__bf16*)take((size_t)N_NODES * DIM * 2);
  __bf16* h_lo    = (__bf16*)take((size_t)N_NODES * DIM * 2);
  float*  y2      = (float*)take((size_t)N_NODES * DIM * 4);
  __bf16* y1h     = (__bf16*)take((size_t)N_NODES * TWO_D * 2);
  __bf16* z_hi    = (__bf16*)take((size_t)N_NODES * DIM * 2);
  __bf16* z_lo    = (__bf16*)take((size_t)N_NODES * DIM * 2);
  int*    csr_src = (int*)take((size_t)N_EDGES * 4);
  __bf16* ea_csr  = (__bf16*)take((size_t)N_EDGES * 8 * 2);
  int*    perm    = (int*)take((size_t)N_EDGES * 4);
  int*    offsets = (int*)take((size_t)(N_NODES + 1) * 4);
  int*    slocal  = (int*)take((size_t)(N_NODES + 1024) * 4);
  int*    sbsum   = (int*)take(64 * 4);
  int*    scarry  = sbsum + 32;
  int*    gs      = (int*)take((size_t)(NGRAPH + 1) * 4);
  float*  pooled  = (float*)take((size_t)NGRAPH * DIM * 4);
  float*  tv      = (float*)take((size_t)NGRAPH * TWO_D * 4);
  float*  vnr     = (float*)take((size_t)NGRAPH * DIM * 4);
  float*  vn0     = (float*)take((size_t)NGRAPH * DIM * 4);
  __bf16* encT_hi = (__bf16*)take((size_t)DIM * DIM * 2);
  __bf16* encT_lo = (__bf16*)take((size_t)DIM * DIM * 2);
  __bf16* W1T_hi  = (__bf16*)take((size_t)NLAYER * DIM * TWO_D * 2);
  __bf16* W1T_lo  = (__bf16*)take((size_t)NLAYER * DIM * TWO_D * 2);
  __bf16* W2T_hi  = (__bf16*)take((size_t)NLAYER * TWO_D * DIM * 2);
  __bf16* W2T_lo  = (__bf16*)take((size_t)NLAYER * TWO_D * DIM * 2);
  if (off > ws_size) return;

  const int* srcArr = edge_index;
  const int* dstArr = edge_index + N_EDGES;

  hipMemsetAsync(counts, 0, memset_bytes, stream);

  k_hist<<<N_EDGES / 256, 256, 0, stream>>>(dstArr, counts);
  k_scanA<<<20, 1024, 0, stream>>>(counts, slocal, sbsum);
  k_scanB<<<1, 256, 0, stream>>>(sbsum, scarry, offsets, batch, gs);
  k_scanC<<<20, 1024, 0, stream>>>(slocal, scarry, offsets);
  k_fillA<<<N_EDGES / 256, 256, 0, stream>>>(dstArr, offsets, cursor, perm);
  k_fillB<<<N_EDGES / 256, 256, 0, stream>>>(perm, srcArr, edge_attr, csr_src, ea_csr);
  k_convAll<<<336, 1024, 0, stream>>>(enc_W, mlp_W1, mlp_W2,
      encT_hi, encT_lo, W1T_hi, W1T_lo, W2T_hi, W2T_lo);
  k_vninit<<<(NGRAPH * DIM) / 256, 256, 0, stream>>>(vn_emb, vn0);
  k_enc<<<N_NODES / 32, 128, 0, stream>>>(x, encT_hi, encT_lo, enc_b, vn_emb, h_hi, h_lo);

  for (int l = 0; l < NLAYER; ++l) {
    float* s1  = stats + (size_t)l * 12288;
    float* q1  = s1 + 2048;
    float* s2  = s1 + 4096;
    float* q2  = s1 + 5120;
    float* sv1 = s1 + 6144;
    float* qv1 = s1 + 8192;
    float* sv2 = s1 + 10240;
    float* qv2 = s1 + 11264;
    if (l < NLAYER - 1) {
      if (l == 0)
        k_pool<<<NGRAPH, 1024, 0, stream>>>(h_hi, gs, vn0, vn0, nullptr, nullptr,
            nullptr, nullptr, 0, pooled);
      else {
        float* psv2 = stats + (size_t)(l - 1) * 12288 + 10240;
        float* pqv2 = stats + (size_t)(l - 1) * 12288 + 11264;
        k_pool<<<NGRAPH, 1024, 0, stream>>>(h_hi, gs, vn0, vnr, psv2, pqv2,
            vn_bn2_g + (size_t)(l - 1) * DIM, vn_bn2_b + (size_t)(l - 1) * DIM, 1, pooled);
      }
    }
    k_agg<<<N_NODES / 4, 256, 0, stream>>>(h_hi, h_lo, offsets, csr_src, ea_csr,
        edge_W + (size_t)l * EDIM * DIM, edge_b + (size_t)l * DIM, eps, l, z_hi, z_lo);
    k_gemm1<<<N_NODES / 16, 256, 0, stream>>>(z_hi, z_lo,
        W1T_hi + (size_t)l * DIM * TWO_D, W1T_lo + (size_t)l * DIM * TWO_D,
        mlp_b1 + (size_t)l * TWO_D, y1h, s1, q1);
    k_gemm2<<<N_NODES / 16, 256, 0, stream>>>(y1h,
        W2T_hi + (size_t)l * TWO_D * DIM, W2T_lo + (size_t)l * TWO_D * DIM,
        mlp_b2 + (size_t)l * DIM, s1, q1,
        mlp_bn1_g + (size_t)l * TWO_D, mlp_bn1_b + (size_t)l * TWO_D,
        y2, s2, q2);
    if (l < NLAYER - 1) {
      k_vgemm1<<<NGRAPH, 256, 0, stream>>>(pooled, vn_W1 + (size_t)l * DIM * TWO_D,
          vn_b1 + (size_t)l * TWO_D, tv, sv1, qv1);
      k_vgemm2<<<NGRAPH, 256, 0, stream>>>(tv, sv1, qv1,
          vn_bn1_g + (size_t)l * TWO_D, vn_bn1_b + (size_t)l * TWO_D,
          vn_W2 + (size_t)l * TWO_D * DIM, vn_b2 + (size_t)l * DIM,
          vnr, sv2, qv2);
      k_bn2hin<<<(N_NODES * 32) / 256, 256, 0, stream>>>(y2, s2, q2,
          bn_g + (size_t)l * DIM, bn_b + (size_t)l * DIM,
          vnr, sv2, qv2, vn_bn2_g + (size_t)l * DIM, vn_bn2_b + (size_t)l * DIM,
          batch, h_hi, h_lo);
    } else {
      k_out<<<(N_NODES * 32) / 256, 256, 0, stream>>>(y2, s2, q2,
          bn_g + (size_t)l * DIM, bn_b + (size_t)l * DIM, (float*)d_out);
    }
  }
}